// Round 3
// baseline (1237.833 us; speedup 1.0000x reference)
//
#include <hip/hip_runtime.h>
#include <cstdint>
#include <cmath>

#define N0G 100000
#define N1G 25000
#define N2G 6250
#define E0G 1600000
#define E1G 400000
#define E2G 100000
#define KCH 6
#define NCLS 40
#define RPB 64   // rows per bucket

static inline int cdiv(long a, long b){ return (int)((a + b - 1) / b); }

// ---------------- bucket CSR build ----------------
// bucket b = row >> 6. Packed ebuf entry: (row&63)<<26 | payload(26b).
// payload = col (graph) or edge index (pool). Both < 2^26 here.

__global__ void k_bcount(const int* __restrict__ row, int E, int* __restrict__ bcnt, int nbkt){
  __shared__ int h[2048];
  for (int i = threadIdx.x; i < nbkt; i += blockDim.x) h[i] = 0;
  __syncthreads();
  for (int e = blockIdx.x * blockDim.x + threadIdx.x; e < E; e += gridDim.x * blockDim.x)
    atomicAdd(&h[row[e] >> 6], 1);
  __syncthreads();
  for (int i = threadIdx.x; i < nbkt; i += blockDim.x)
    if (h[i]) atomicAdd(&bcnt[i], h[i]);
}

__global__ void k_bscan(const int* __restrict__ bcnt, int nbkt,
                        int* __restrict__ bko, int* __restrict__ bcur,
                        int* __restrict__ rp, int N){
  __shared__ int sums[256];
  int per = (nbkt + 255) >> 8;           // <= 8 for N <= 131072
  int base = threadIdx.x * per;
  int v[8]; int s = 0;
  for (int j = 0; j < per; j++){ int i = base + j; v[j] = (i < nbkt) ? bcnt[i] : 0; s += v[j]; }
  sums[threadIdx.x] = s;
  __syncthreads();
  for (int o = 1; o < 256; o <<= 1){
    int t = (threadIdx.x >= o) ? sums[threadIdx.x - o] : 0;
    __syncthreads();
    sums[threadIdx.x] += t;
    __syncthreads();
  }
  int excl = sums[threadIdx.x] - s;
  for (int j = 0; j < per; j++){
    int i = base + j;
    if (i < nbkt){ bko[i] = excl; bcur[i] = excl; excl += v[j]; }
  }
  if (threadIdx.x == 255){ bko[nbkt] = sums[255]; rp[N] = sums[255]; }
}

template<bool POOL>
__global__ void k_bscatter(const int* __restrict__ row, const int* __restrict__ col, int E,
                           int* __restrict__ bcur, unsigned* __restrict__ ebuf){
  int e = blockIdx.x * blockDim.x + threadIdx.x;
  if (e >= E) return;
  int r = row[e];
  int p = atomicAdd(&bcur[r >> 6], 1);
  unsigned pay = POOL ? (unsigned)e : (unsigned)col[e];
  ebuf[p] = ((unsigned)(r & 63) << 26) | pay;
}

template<bool POOL>
__global__ void k_bfinal(const unsigned* __restrict__ ebuf, const int* __restrict__ bko, int N,
                         const int* __restrict__ pcol, const float* __restrict__ pval,
                         int* __restrict__ rp, float* __restrict__ dinv,
                         int* __restrict__ cs, float* __restrict__ wv){
  __shared__ int h[RPB];
  __shared__ int cur[RPB];
  int b = blockIdx.x;
  int e0 = bko[b], e1 = bko[b + 1];
  int r0 = b * RPB;
  if (threadIdx.x < RPB) h[threadIdx.x] = 0;
  __syncthreads();
  for (int e = e0 + threadIdx.x; e < e1; e += 256)
    atomicAdd(&h[ebuf[e] >> 26], 1);
  __syncthreads();
  if (threadIdx.x < 64){
    int lane = threadIdx.x;
    int cnt = h[lane];
    int v = cnt;
    for (int o = 1; o < 64; o <<= 1){
      int t = __shfl_up(v, o);
      if (lane >= o) v += t;
    }
    int excl = v - cnt;
    cur[lane] = excl;
    if (r0 + lane < N){
      rp[r0 + lane] = e0 + excl;
      if (!POOL) dinv[r0 + lane] = cnt > 0 ? rsqrtf((float)cnt) : 0.f;
    }
  }
  __syncthreads();
  for (int e = e0 + threadIdx.x; e < e1; e += 256){
    unsigned u = ebuf[e];
    int p = atomicAdd(&cur[u >> 26], 1);
    int dst = e0 + p;
    if (POOL){
      int ei = (int)(u & 0x3FFFFFFu);
      cs[dst] = pcol[ei]; wv[dst] = pval[ei];
    } else {
      cs[dst] = (int)(u & 0x3FFFFFFu);
    }
  }
}

// ---------------- CSR gather: graph layers (weight = dinv[col], epilogue -scale*dinv[n]*acc - sub) ----------------
__global__ void k_gather3(const int* __restrict__ rp, const int* __restrict__ cs,
                          const float* __restrict__ src, const float* __restrict__ dinv,
                          const float* __restrict__ sub, float* __restrict__ dst,
                          int N, float scale){
  int n = blockIdx.x * blockDim.x + threadIdx.x;
  if (n >= N) return;
  int e0 = rp[n], e1 = rp[n + 1];
  float a0 = 0.f, a1 = 0.f, a2 = 0.f;
  for (int e = e0; e < e1; e++){
    int c = cs[e];
    float w = dinv[c];
    const float* sp = src + c * 3;
    a0 = fmaf(w, sp[0], a0);
    a1 = fmaf(w, sp[1], a1);
    a2 = fmaf(w, sp[2], a2);
  }
  float m = -scale * dinv[n];
  float r0 = m * a0, r1 = m * a1, r2 = m * a2;
  if (sub){ r0 -= sub[n * 3 + 0]; r1 -= sub[n * 3 + 1]; r2 -= sub[n * 3 + 2]; }
  dst[n * 3 + 0] = r0; dst[n * 3 + 1] = r1; dst[n * 3 + 2] = r2;
}

template<int F>
__global__ void k_gatherT(const int* __restrict__ rp, const int* __restrict__ cs,
                          const float* __restrict__ src, const float* __restrict__ dinv,
                          const float* __restrict__ sub, float* __restrict__ dst,
                          int N, float scale){
  int n = blockIdx.x * (256 / F) + threadIdx.x / F;
  int f = threadIdx.x % F;
  if (n >= N) return;
  int e0 = rp[n], e1 = rp[n + 1];
  float acc = 0.f;
  for (int e = e0; e < e1; e++){
    int c = cs[e];
    acc = fmaf(dinv[c], src[(long)c * F + f], acc);
  }
  float t = -scale * dinv[n] * acc;
  if (sub) t -= sub[(long)n * F + f];
  dst[(long)n * F + f] = t;
}

// ---------------- CSR gather: pools (weight = wv) ----------------
template<int F>
__global__ void k_gatherP(const int* __restrict__ rp, const int* __restrict__ cs,
                          const float* __restrict__ wv, const float* __restrict__ h,
                          float* __restrict__ dst, int N){
  int n = blockIdx.x * (256 / F) + threadIdx.x / F;
  int f = threadIdx.x % F;
  if (n >= N) return;
  int e0 = rp[n], e1 = rp[n + 1];
  float acc = 0.f;
  for (int e = e0; e < e1; e++){
    int c = cs[e];
    acc = fmaf(wv[e], h[(long)c * F + f], acc);
  }
  dst[(long)n * F + f] = acc;
}

// ---------------- dense cheb contraction ----------------
// out[n,o] = b[o] + sum_f x[n,f]*W[0][f,o] + sum_{k=1..5,f} T[k-1][n,f]*W[k][f,o]
template<int F, int FO, bool RELU>
__global__ void k_cheb_out(const float* __restrict__ x, const float* __restrict__ T, int N,
                           const float* __restrict__ W, const float* __restrict__ b,
                           float* __restrict__ out){
  long t = (long)blockIdx.x * blockDim.x + threadIdx.x;
  int n = (int)(t / FO), o = (int)(t % FO);
  if (n >= N) return;
  float acc = b[o];
  const float* xr = x + (long)n * F;
  const float* W0 = W + o;
  for (int f = 0; f < F; f++)
    acc = fmaf(xr[f], W0[(long)f * FO], acc);
  for (int k = 1; k < KCH; k++){
    const float* Tk = T + ((long)(k - 1) * N + n) * F;
    const float* Wk = W + (long)k * F * FO + o;
    for (int f = 0; f < F; f++)
      acc = fmaf(Tk[f], Wk[(long)f * FO], acc);
  }
  out[(long)n * FO + o] = RELU ? fmaxf(acc, 0.f) : acc;
}

// ---------------- final hidden GEMM + global max + classifier ----------------
__device__ __forceinline__ unsigned fmap(float x){
  unsigned u = __float_as_uint(x);
  return (u & 0x80000000u) ? ~u : (u | 0x80000000u);
}
__device__ __forceinline__ float funmap(unsigned u){
  return (u & 0x80000000u) ? __uint_as_float(u ^ 0x80000000u) : __uint_as_float(~u);
}

__global__ void k_init_max(unsigned* __restrict__ m){
  m[blockIdx.x * blockDim.x + threadIdx.x] = fmap(-INFINITY);
}

#define NB 25
__global__ void k_hidden_max(const float* __restrict__ h2, const float* __restrict__ Wh,
                             const float* __restrict__ bh, unsigned* __restrict__ maxed, int N){
  __shared__ float sh[NB * 128];
  int o  = blockIdx.x * 256 + threadIdx.x;
  int n0 = blockIdx.y * NB;
  for (int i = threadIdx.x; i < NB * 128; i += 256){
    int n = n0 + i / 128;
    sh[i] = (n < N) ? h2[(long)n * 128 + (i & 127)] : 0.f;
  }
  __syncthreads();
  float acc[NB];
#pragma unroll
  for (int n = 0; n < NB; n++) acc[n] = 0.f;
  for (int f = 0; f < 128; f++){
    float w = Wh[(long)f * 1024 + o];
#pragma unroll
    for (int n = 0; n < NB; n++) acc[n] = fmaf(sh[n * 128 + f], w, acc[n]);
  }
  float bo = bh[o];
  float m = -INFINITY;
#pragma unroll
  for (int n = 0; n < NB; n++)
    if (n0 + n < N) m = fmaxf(m, acc[n] + bo);
  atomicMax(&maxed[o], fmap(m));
}

__global__ void k_final(const unsigned* __restrict__ maxed, const float* __restrict__ Wl,
                        const float* __restrict__ bl, float* __restrict__ out){
  int c = threadIdx.x;
  if (c >= NCLS) return;
  float acc = bl[c];
  for (int o = 0; o < 1024; o++)
    acc = fmaf(funmap(maxed[o]), Wl[o * NCLS + c], acc);
  out[c] = acc;
}

// ---------------- drivers ----------------
template<int F, int FO, bool RELU>
static void run_cheb(const int* row, const int* col, int E, int N,
                     const float* x, const float* W, const float* b, float* out,
                     unsigned* ebuf, int* cs, float* T,
                     int* rp, float* dinv, int* bcnt, int* bko, int* bcur,
                     hipStream_t s){
  const int B = 256;
  int nbkt = cdiv(N, RPB);
  hipMemsetAsync(bcnt, 0, (size_t)nbkt * sizeof(int), s);
  k_bcount<<<128, 256, 0, s>>>(row, E, bcnt, nbkt);
  k_bscan<<<1, 256, 0, s>>>(bcnt, nbkt, bko, bcur, rp, N);
  k_bscatter<false><<<cdiv(E, B), B, 0, s>>>(row, col, E, bcur, ebuf);
  k_bfinal<false><<<nbkt, 256, 0, s>>>(ebuf, bko, N, nullptr, nullptr, rp, dinv, cs, nullptr);

  const float* src = x; const float* sub = nullptr; float scale = 1.f;
  for (int k = 1; k < KCH; k++){
    float* Tk = T + (size_t)(k - 1) * N * F;
    if constexpr (F == 3)
      k_gather3<<<cdiv(N, B), B, 0, s>>>(rp, cs, src, dinv, sub, Tk, N, scale);
    else
      k_gatherT<F><<<cdiv(N, 256 / F), 256, 0, s>>>(rp, cs, src, dinv, sub, Tk, N, scale);
    sub = src; src = Tk; scale = 2.f;
  }
  k_cheb_out<F, FO, RELU><<<cdiv((long)N * FO, B), B, 0, s>>>(x, T, N, W, b, out);
}

template<int F>
static void run_pool(const int* row, const int* col, const float* val, int E, int Nout,
                     const float* h, float* out, unsigned* ebuf, int* cs, float* wv,
                     int* rp, int* bcnt, int* bko, int* bcur, hipStream_t s){
  const int B = 256;
  int nbkt = cdiv(Nout, RPB);
  hipMemsetAsync(bcnt, 0, (size_t)nbkt * sizeof(int), s);
  k_bcount<<<128, 256, 0, s>>>(row, E, bcnt, nbkt);
  k_bscan<<<1, 256, 0, s>>>(bcnt, nbkt, bko, bcur, rp, Nout);
  k_bscatter<true><<<cdiv(E, B), B, 0, s>>>(row, col, E, bcur, ebuf);
  k_bfinal<true><<<nbkt, 256, 0, s>>>(ebuf, bko, Nout, col, val, rp, nullptr, cs, wv);
  k_gatherP<F><<<cdiv(Nout, 256 / F), 256, 0, s>>>(rp, cs, wv, h, out, Nout);
}

extern "C" void kernel_launch(void* const* d_in, const int* in_sizes, int n_in,
                              void* d_out, int out_size, void* d_ws, size_t ws_size,
                              hipStream_t stream){
  const float* pos = (const float*)d_in[0];
  const int*   ei0 = (const int*)d_in[1];
  const int*   ei1 = (const int*)d_in[2];
  const int*   ei2 = (const int*)d_in[3];
  const int*   p0r = (const int*)d_in[4];
  const int*   p0c = (const int*)d_in[5];
  const float* p0v = (const float*)d_in[6];
  const int*   p1r = (const int*)d_in[7];
  const int*   p1c = (const int*)d_in[8];
  const float* p1v = (const float*)d_in[9];
  const float* W0  = (const float*)d_in[10]; const float* b0 = (const float*)d_in[11];
  const float* W1  = (const float*)d_in[12]; const float* b1 = (const float*)d_in[13];
  const float* W2  = (const float*)d_in[14]; const float* b2 = (const float*)d_in[15];
  const float* Wh  = (const float*)d_in[16]; const float* bh = (const float*)d_in[17];
  const float* Wl  = (const float*)d_in[18]; const float* bl = (const float*)d_in[19];
  float* out = (float*)d_out;

  // workspace layout (float-sized units). Total ~10.6M floats = 42.4MB.
  float* SCR = (float*)d_ws;                 // 4.8M floats, per-stage overlays
  float* hA  = SCR + 4800000;                // 3.2M  (N0*32 / N2*128)
  float* hB  = hA + 3200000;                 // 1.6M  (N1*64)
  float* hC  = hB + 1600000;                 // 0.8M  (N1*32 / N2*64)
  int* rp     = (int*)(hC + 800000);         // 100001
  float* dinv = (float*)(rp + 100001);       // 100000
  int* bcnt   = (int*)(dinv + 100000);       // 2048
  int* bko    = bcnt + 2048;                 // 2049
  int* bcur   = bko + 2049;                  // 2048
  unsigned* maxed = (unsigned*)(bcur + 2048);// 1024

  // layer 0: cheb(pos) -> hA [N0,32], relu.  SCR: ebuf 1.6M | cs 1.6M | T 1.5M
  run_cheb<3, 32, true>(ei0, ei0 + E0G, E0G, N0G, pos, W0, b0, hA,
                        (unsigned*)SCR, (int*)(SCR + 1600000), SCR + 3200000,
                        rp, dinv, bcnt, bko, bcur, stream);

  // pool 0: hA -> hC [N1,32].  SCR: ebuf 100K | cs 100K | wv 100K
  run_pool<32>(p0r, p0c, p0v, N0G, N1G, hA, hC,
               (unsigned*)SCR, (int*)(SCR + 100000), SCR + 200000,
               rp, bcnt, bko, bcur, stream);

  // layer 1: cheb(hC) -> hB [N1,64], relu.  SCR: ebuf 400K | cs 400K | T 4M
  run_cheb<32, 64, true>(ei1, ei1 + E1G, E1G, N1G, hC, W1, b1, hB,
                         (unsigned*)SCR, (int*)(SCR + 400000), SCR + 800000,
                         rp, dinv, bcnt, bko, bcur, stream);

  // pool 1: hB -> hC [N2,64].  SCR: ebuf 25K | cs 25K | wv 25K
  run_pool<64>(p1r, p1c, p1v, N1G, N2G, hB, hC,
               (unsigned*)SCR, (int*)(SCR + 25000), SCR + 50000,
               rp, bcnt, bko, bcur, stream);

  // layer 2: cheb(hC) -> hA [N2,128], no relu.  SCR: ebuf 100K | cs 100K | T 2M
  run_cheb<64, 128, false>(ei2, ei2 + E2G, E2G, N2G, hC, W2, b2, hA,
                           (unsigned*)SCR, (int*)(SCR + 100000), SCR + 200000,
                           rp, dinv, bcnt, bko, bcur, stream);

  // hidden GEMM + global max over nodes
  k_init_max<<<4, 256, 0, stream>>>(maxed);
  dim3 g(4, 250);
  k_hidden_max<<<g, 256, 0, stream>>>(hA, Wh, bh, maxed, N2G);

  // classifier
  k_final<<<1, 64, 0, stream>>>(maxed, Wl, bl, out);
}

// Round 4
// 724.341 us; speedup vs baseline: 1.7089x; 1.7089x over previous
//
#include <hip/hip_runtime.h>
#include <cstdint>
#include <cmath>

#define N0G 100000
#define N1G 25000
#define N2G 6250
#define E0G 1600000
#define E1G 400000
#define E2G 100000
#define KCH 6
#define NCLS 40
#define RPB 512            // rows per bucket (9 bits local row)
#define NBLK 240           // binning blocks
#define PAYB 17            // payload bits (col or edge idx < 131072)

static inline int cdiv(long a, long b){ return (int)((a + b - 1) / b); }

// ================= deterministic bucket CSR build =================
// entry = (row & 511) << 17 | payload.  payload = col (graph) or edge idx (pool)

__global__ __launch_bounds__(256) void k_phist(const int* __restrict__ row, int E, int chunk,
                                               int* __restrict__ gh, int nbkt){
  __shared__ int h[256];
  for (int i = threadIdx.x; i < nbkt; i += 256) h[i] = 0;
  __syncthreads();
  int e0 = blockIdx.x * chunk, e1 = min(E, e0 + chunk);
  for (int e = e0 + threadIdx.x; e < e1; e += 256)
    atomicAdd(&h[row[e] >> 9], 1);
  __syncthreads();
  for (int i = threadIdx.x; i < nbkt; i += 256)
    gh[i * NBLK + blockIdx.x] = h[i];
}

__global__ __launch_bounds__(1024) void k_pscan(int* __restrict__ gh, int M,
                                                int* __restrict__ rp, int N, int E){
  __shared__ int sums[1024];
  int per = (M + 1023) >> 10;
  int base = threadIdx.x * per;
  int s = 0;
  for (int j = 0; j < per; j++){ int i = base + j; if (i < M) s += gh[i]; }
  sums[threadIdx.x] = s;
  __syncthreads();
  for (int o = 1; o < 1024; o <<= 1){
    int t = (threadIdx.x >= o) ? sums[threadIdx.x - o] : 0;
    __syncthreads();
    sums[threadIdx.x] += t;
    __syncthreads();
  }
  int excl = sums[threadIdx.x] - s;
  for (int j = 0; j < per; j++){
    int i = base + j;
    if (i < M){ int v = gh[i]; gh[i] = excl; excl += v; }
  }
  if (threadIdx.x == 0) rp[N] = E;
}

template<bool POOL>
__global__ __launch_bounds__(256) void k_pscatter(const int* __restrict__ row, const int* __restrict__ col,
                                                  int E, int chunk, const int* __restrict__ gh,
                                                  unsigned* __restrict__ ebuf, int nbkt){
  __shared__ int cur[256];
  for (int i = threadIdx.x; i < nbkt; i += 256) cur[i] = gh[i * NBLK + blockIdx.x];
  __syncthreads();
  int e0 = blockIdx.x * chunk, e1 = min(E, e0 + chunk);
  for (int e = e0 + threadIdx.x; e < e1; e += 256){
    int r = row[e];
    int dst = atomicAdd(&cur[r >> 9], 1);
    unsigned pay = POOL ? (unsigned)e : (unsigned)col[e];
    ebuf[dst] = ((unsigned)(r & 511) << PAYB) | pay;
  }
}

template<bool POOL>
__global__ __launch_bounds__(512) void k_bfinal(const unsigned* __restrict__ ebuf,
                                                const int* __restrict__ gh, int nbkt, int N, int E,
                                                const int* __restrict__ pcol, const float* __restrict__ pval,
                                                int* __restrict__ rp, float* __restrict__ dinv,
                                                int* __restrict__ cs, float* __restrict__ wv){
  __shared__ int h[512];
  __shared__ int cur[512];
  int b = blockIdx.x;
  int e0 = gh[b * NBLK];
  int e1 = (b + 1 < nbkt) ? gh[(b + 1) * NBLK] : E;
  int r0 = b * RPB;
  int t = threadIdx.x;
  h[t] = 0;
  __syncthreads();
  for (int e = e0 + t; e < e1; e += 512)
    atomicAdd(&h[ebuf[e] >> PAYB], 1);
  __syncthreads();
  int cnt = h[t];
  __syncthreads();
  for (int o = 1; o < 512; o <<= 1){
    int tmp = (t >= o) ? h[t - o] : 0;
    __syncthreads();
    h[t] += tmp;
    __syncthreads();
  }
  int excl = h[t] - cnt;
  cur[t] = excl;
  if (r0 + t < N){
    rp[r0 + t] = e0 + excl;
    if (!POOL) dinv[r0 + t] = cnt > 0 ? rsqrtf((float)cnt) : 0.f;
  }
  __syncthreads();
  for (int e = e0 + t; e < e1; e += 512){
    unsigned u = ebuf[e];
    int p = atomicAdd(&cur[u >> PAYB], 1);
    int dst = e0 + p;
    if (POOL){
      int ei = (int)(u & ((1u << PAYB) - 1));
      cs[dst] = pcol[ei]; wv[dst] = pval[ei];
    } else {
      cs[dst] = (int)(u & ((1u << PAYB) - 1));
    }
  }
}

// ================= CSR gathers =================
__global__ __launch_bounds__(256) void k_gather3(const int* __restrict__ rp, const int* __restrict__ cs,
                          const float* __restrict__ src, const float* __restrict__ dinv,
                          const float* __restrict__ sub, float* __restrict__ dst,
                          int N, float scale){
  int n = blockIdx.x * blockDim.x + threadIdx.x;
  if (n >= N) return;
  int e0 = rp[n], e1 = rp[n + 1];
  float a0 = 0.f, a1 = 0.f, a2 = 0.f;
  for (int e = e0; e < e1; e++){
    int c = cs[e];
    float w = dinv[c];
    const float* sp = src + c * 3;
    a0 = fmaf(w, sp[0], a0);
    a1 = fmaf(w, sp[1], a1);
    a2 = fmaf(w, sp[2], a2);
  }
  float m = -scale * dinv[n];
  float r0 = m * a0, r1 = m * a1, r2 = m * a2;
  if (sub){ r0 -= sub[n * 3 + 0]; r1 -= sub[n * 3 + 1]; r2 -= sub[n * 3 + 2]; }
  dst[n * 3 + 0] = r0; dst[n * 3 + 1] = r1; dst[n * 3 + 2] = r2;
}

// F multiple of 4; lane-group of L=F/4 per node, float4 per lane.
template<int F>
__global__ __launch_bounds__(256) void k_gatherT(const int* __restrict__ rp, const int* __restrict__ cs,
                          const float* __restrict__ src, const float* __restrict__ dinv,
                          const float* __restrict__ sub, float* __restrict__ dst,
                          int N, float scale){
  constexpr int L = F / 4;
  int tid = blockIdx.x * 256 + threadIdx.x;
  int n = tid / L, q = tid % L;
  if (n >= N) return;
  const float4* src4 = (const float4*)src;
  int e0 = rp[n], e1 = rp[n + 1];
  float4 acc = make_float4(0.f, 0.f, 0.f, 0.f);
  for (int e = e0; e < e1; e++){
    int c = cs[e];
    float w = dinv[c];
    float4 v = src4[(long)c * L + q];
    acc.x = fmaf(w, v.x, acc.x); acc.y = fmaf(w, v.y, acc.y);
    acc.z = fmaf(w, v.z, acc.z); acc.w = fmaf(w, v.w, acc.w);
  }
  float m = -scale * dinv[n];
  float4 r = make_float4(m * acc.x, m * acc.y, m * acc.z, m * acc.w);
  if (sub){
    float4 sv = ((const float4*)sub)[(long)n * L + q];
    r.x -= sv.x; r.y -= sv.y; r.z -= sv.z; r.w -= sv.w;
  }
  ((float4*)dst)[(long)n * L + q] = r;
}

template<int F>
__global__ __launch_bounds__(256) void k_gatherP(const int* __restrict__ rp, const int* __restrict__ cs,
                          const float* __restrict__ wv, const float* __restrict__ h,
                          float* __restrict__ dst, int N){
  constexpr int L = F / 4;
  int tid = blockIdx.x * 256 + threadIdx.x;
  int n = tid / L, q = tid % L;
  if (n >= N) return;
  const float4* h4 = (const float4*)h;
  int e0 = rp[n], e1 = rp[n + 1];
  float4 acc = make_float4(0.f, 0.f, 0.f, 0.f);
  for (int e = e0; e < e1; e++){
    int c = cs[e];
    float w = wv[e];
    float4 v = h4[(long)c * L + q];
    acc.x = fmaf(w, v.x, acc.x); acc.y = fmaf(w, v.y, acc.y);
    acc.z = fmaf(w, v.z, acc.z); acc.w = fmaf(w, v.w, acc.w);
  }
  ((float4*)dst)[(long)n * L + q] = acc;
}

// ================= dense cheb contraction (4 outputs/thread) =================
// out[n, 4q..4q+3] = b + sum_f x[n,f]*W[0][f,:] + sum_{k>=1,f} T[k-1][n,f]*W[k][f,:]
template<int F, int FO, bool RELU>
__global__ __launch_bounds__(256) void k_cheb_out(const float* __restrict__ x, const float* __restrict__ T, int N,
                           const float* __restrict__ W, const float* __restrict__ b,
                           float* __restrict__ out){
  constexpr int OQ = FO / 4;
  long t = (long)blockIdx.x * 256 + threadIdx.x;
  int n = (int)(t / OQ), q = (int)(t % OQ);
  if (n >= N) return;
  const float4* W4 = (const float4*)W;
  float4 acc = ((const float4*)b)[q];
  for (int k = 0; k < KCH; k++){
    const float* row = (k == 0) ? (x + (long)n * F) : (T + ((long)(k - 1) * N + n) * F);
    const float4* Wk = W4 + (long)k * F * OQ + q;
    for (int f = 0; f < F; f++){
      float v = row[f];
      float4 w = Wk[(long)f * OQ];
      acc.x = fmaf(v, w.x, acc.x); acc.y = fmaf(v, w.y, acc.y);
      acc.z = fmaf(v, w.z, acc.z); acc.w = fmaf(v, w.w, acc.w);
    }
  }
  if (RELU){
    acc.x = fmaxf(acc.x, 0.f); acc.y = fmaxf(acc.y, 0.f);
    acc.z = fmaxf(acc.z, 0.f); acc.w = fmaxf(acc.w, 0.f);
  }
  ((float4*)out)[(long)n * OQ + q] = acc;
}

// ================= final hidden GEMM + global max + classifier =================
__device__ __forceinline__ unsigned fmap(float x){
  unsigned u = __float_as_uint(x);
  return (u & 0x80000000u) ? ~u : (u | 0x80000000u);
}
__device__ __forceinline__ float funmap(unsigned u){
  return (u & 0x80000000u) ? __uint_as_float(u ^ 0x80000000u) : __uint_as_float(~u);
}

__global__ void k_init_max(unsigned* __restrict__ m){
  m[blockIdx.x * blockDim.x + threadIdx.x] = fmap(-INFINITY);
}

#define NB 25
__global__ __launch_bounds__(256) void k_hidden_max(const float* __restrict__ h2, const float* __restrict__ Wh,
                             const float* __restrict__ bh, unsigned* __restrict__ maxed, int N){
  __shared__ float sh[NB * 128];
  int o  = blockIdx.x * 256 + threadIdx.x;
  int n0 = blockIdx.y * NB;
  for (int i = threadIdx.x; i < NB * 128; i += 256){
    int n = n0 + i / 128;
    sh[i] = (n < N) ? h2[(long)n * 128 + (i & 127)] : 0.f;
  }
  __syncthreads();
  float acc[NB];
#pragma unroll
  for (int n = 0; n < NB; n++) acc[n] = 0.f;
  for (int f = 0; f < 128; f++){
    float w = Wh[(long)f * 1024 + o];
#pragma unroll
    for (int n = 0; n < NB; n++) acc[n] = fmaf(sh[n * 128 + f], w, acc[n]);
  }
  float bo = bh[o];
  float m = -INFINITY;
#pragma unroll
  for (int n = 0; n < NB; n++)
    if (n0 + n < N) m = fmaxf(m, acc[n] + bo);
  atomicMax(&maxed[o], fmap(m));
}

__global__ void k_final(const unsigned* __restrict__ maxed, const float* __restrict__ Wl,
                        const float* __restrict__ bl, float* __restrict__ out){
  int c = threadIdx.x;
  if (c >= NCLS) return;
  float acc = bl[c];
  for (int o = 0; o < 1024; o++)
    acc = fmaf(funmap(maxed[o]), Wl[o * NCLS + c], acc);
  out[c] = acc;
}

// ================= drivers =================
static void build_bins(const int* row, const int* col, int E, int N, bool pool,
                       int* gh, unsigned* ebuf, hipStream_t s){
  int nbkt = cdiv(N, RPB);
  int chunk = cdiv(E, NBLK);
  k_phist<<<NBLK, 256, 0, s>>>(row, E, chunk, gh, nbkt);
  // scan happens in caller (needs rp)
  (void)col; (void)pool; (void)ebuf;
}

template<int F, int FO, bool RELU>
static void run_cheb(const int* row, const int* col, int E, int N,
                     const float* x, const float* W, const float* b, float* out,
                     unsigned* ebuf, int* cs, float* T,
                     int* rp, float* dinv, int* gh, hipStream_t s){
  int nbkt = cdiv(N, RPB);
  int chunk = cdiv(E, NBLK);
  k_phist<<<NBLK, 256, 0, s>>>(row, E, chunk, gh, nbkt);
  k_pscan<<<1, 1024, 0, s>>>(gh, nbkt * NBLK, rp, N, E);
  k_pscatter<false><<<NBLK, 256, 0, s>>>(row, col, E, chunk, gh, ebuf, nbkt);
  k_bfinal<false><<<nbkt, 512, 0, s>>>(ebuf, gh, nbkt, N, E, nullptr, nullptr, rp, dinv, cs, nullptr);

  const float* src = x; const float* sub = nullptr; float scale = 1.f;
  for (int k = 1; k < KCH; k++){
    float* Tk = T + (size_t)(k - 1) * N * F;
    if constexpr (F == 3)
      k_gather3<<<cdiv(N, 256), 256, 0, s>>>(rp, cs, src, dinv, sub, Tk, N, scale);
    else
      k_gatherT<F><<<cdiv((long)N * (F / 4), 256), 256, 0, s>>>(rp, cs, src, dinv, sub, Tk, N, scale);
    sub = src; src = Tk; scale = 2.f;
  }
  k_cheb_out<F, FO, RELU><<<cdiv((long)N * (FO / 4), 256), 256, 0, s>>>(x, T, N, W, b, out);
}

template<int F>
static void run_pool(const int* row, const int* col, const float* val, int E, int Nout,
                     const float* h, float* out, unsigned* ebuf, int* cs, float* wv,
                     int* rp, int* gh, hipStream_t s){
  int nbkt = cdiv(Nout, RPB);
  int chunk = cdiv(E, NBLK);
  k_phist<<<NBLK, 256, 0, s>>>(row, E, chunk, gh, nbkt);
  k_pscan<<<1, 1024, 0, s>>>(gh, nbkt * NBLK, rp, Nout, E);
  k_pscatter<true><<<NBLK, 256, 0, s>>>(row, col, E, chunk, gh, ebuf, nbkt);
  k_bfinal<true><<<nbkt, 512, 0, s>>>(ebuf, gh, nbkt, Nout, E, col, val, rp, nullptr, cs, wv);
  k_gatherP<F><<<cdiv((long)Nout * (F / 4), 256), 256, 0, s>>>(rp, cs, wv, h, out, Nout);
}

extern "C" void kernel_launch(void* const* d_in, const int* in_sizes, int n_in,
                              void* d_out, int out_size, void* d_ws, size_t ws_size,
                              hipStream_t stream){
  const float* pos = (const float*)d_in[0];
  const int*   ei0 = (const int*)d_in[1];
  const int*   ei1 = (const int*)d_in[2];
  const int*   ei2 = (const int*)d_in[3];
  const int*   p0r = (const int*)d_in[4];
  const int*   p0c = (const int*)d_in[5];
  const float* p0v = (const float*)d_in[6];
  const int*   p1r = (const int*)d_in[7];
  const int*   p1c = (const int*)d_in[8];
  const float* p1v = (const float*)d_in[9];
  const float* W0  = (const float*)d_in[10]; const float* b0 = (const float*)d_in[11];
  const float* W1  = (const float*)d_in[12]; const float* b1 = (const float*)d_in[13];
  const float* W2  = (const float*)d_in[14]; const float* b2 = (const float*)d_in[15];
  const float* Wh  = (const float*)d_in[16]; const float* bh = (const float*)d_in[17];
  const float* Wl  = (const float*)d_in[18]; const float* bl = (const float*)d_in[19];
  float* out = (float*)d_out;

  // workspace layout (float-sized units)
  float* SCR = (float*)d_ws;                 // 4.8M floats, per-stage overlays
  float* hA  = SCR + 4800000;                // 3.2M  (N0*32 / N2*128)
  float* hB  = hA + 3200000;                 // 1.6M  (N1*64)
  float* hC  = hB + 1600000;                 // 0.8M  (N1*32 / N2*64)
  int* rp     = (int*)(hC + 800000);         // 100001
  float* dinv = (float*)(rp + 100001);       // 100000
  int* gh     = (int*)(dinv + 100000);       // 47040 (196*240 max)
  unsigned* maxed = (unsigned*)(gh + 47040); // 1024

  // layer 0: cheb(pos) -> hA [N0,32], relu.  SCR: ebuf 1.6M | cs 1.6M | T 1.5M
  run_cheb<3, 32, true>(ei0, ei0 + E0G, E0G, N0G, pos, W0, b0, hA,
                        (unsigned*)SCR, (int*)(SCR + 1600000), SCR + 3200000,
                        rp, dinv, gh, stream);

  // pool 0: hA -> hC [N1,32].  SCR: ebuf 100K | cs 100K | wv 100K
  run_pool<32>(p0r, p0c, p0v, N0G, N1G, hA, hC,
               (unsigned*)SCR, (int*)(SCR + 100000), SCR + 200000,
               rp, gh, stream);

  // layer 1: cheb(hC) -> hB [N1,64], relu.  SCR: ebuf 400K | cs 400K | T 4M
  run_cheb<32, 64, true>(ei1, ei1 + E1G, E1G, N1G, hC, W1, b1, hB,
                         (unsigned*)SCR, (int*)(SCR + 400000), SCR + 800000,
                         rp, dinv, gh, stream);

  // pool 1: hB -> hC [N2,64].  SCR: ebuf 25K | cs 25K | wv 25K
  run_pool<64>(p1r, p1c, p1v, N1G, N2G, hB, hC,
               (unsigned*)SCR, (int*)(SCR + 25000), SCR + 50000,
               rp, gh, stream);

  // layer 2: cheb(hC) -> hA [N2,128], no relu.  SCR: ebuf 100K | cs 100K | T 2M
  run_cheb<64, 128, false>(ei2, ei2 + E2G, E2G, N2G, hC, W2, b2, hA,
                           (unsigned*)SCR, (int*)(SCR + 100000), SCR + 200000,
                           rp, dinv, gh, stream);

  // hidden GEMM + global max over nodes
  k_init_max<<<4, 256, 0, stream>>>(maxed);
  dim3 g(4, 250);
  k_hidden_max<<<g, 256, 0, stream>>>(hA, Wh, bh, maxed, N2G);

  // classifier
  k_final<<<1, 64, 0, stream>>>(maxed, Wl, bl, out);
}

// Round 5
// 649.903 us; speedup vs baseline: 1.9046x; 1.1145x over previous
//
#include <hip/hip_runtime.h>
#include <cstdint>
#include <cmath>

#define N0G 100000
#define N1G 25000
#define N2G 6250
#define E0G 1600000
#define E1G 400000
#define E2G 100000
#define KCH 6
#define NCLS 40
#define RPB 512            // rows per bucket (9 bits local row)
#define NBLK 240           // binning blocks
#define PAYB 17            // payload bits (col or edge idx < 131072)
#define SCT 16             // scan elems per thread
#define SCB (256 * SCT)    // scan elems per block

static inline int cdiv(long a, long b){ return (int)((a + b - 1) / b); }

// ================= deterministic bucket CSR build =================
// entry = (row & 511) << 17 | payload.  payload = col (graph) or edge idx (pool)

__global__ __launch_bounds__(256) void k_phist(const int* __restrict__ row, int E, int chunk,
                                               int* __restrict__ gh, int nbkt){
  __shared__ int h[256];
  for (int i = threadIdx.x; i < nbkt; i += 256) h[i] = 0;
  __syncthreads();
  int e0 = blockIdx.x * chunk, e1 = min(E, e0 + chunk);
  for (int e = e0 + threadIdx.x; e < e1; e += 256)
    atomicAdd(&h[row[e] >> 9], 1);
  __syncthreads();
  for (int i = threadIdx.x; i < nbkt; i += 256)
    gh[i * NBLK + blockIdx.x] = h[i];
}

// parallel flat exclusive scan of gh[M]: A) per-block sums, C) offset + local scan
__global__ __launch_bounds__(256) void k_scanA(const int* __restrict__ gh, int M, int* __restrict__ bsum){
  __shared__ int sh[256];
  int base = blockIdx.x * SCB + threadIdx.x * SCT;
  int s = 0;
#pragma unroll
  for (int j = 0; j < SCT; j++){ int i = base + j; if (i < M) s += gh[i]; }
  sh[threadIdx.x] = s; __syncthreads();
  for (int o = 128; o > 0; o >>= 1){
    if (threadIdx.x < o) sh[threadIdx.x] += sh[threadIdx.x + o];
    __syncthreads();
  }
  if (threadIdx.x == 0) bsum[blockIdx.x] = sh[0];
}

__global__ __launch_bounds__(256) void k_scanC(int* __restrict__ gh, int M, const int* __restrict__ bsum,
                                               int* __restrict__ rp, int N, int E){
  __shared__ int sh[256];
  __shared__ int blockoff;
  if (threadIdx.x == 0){
    int off = 0;
    for (int j = 0; j < (int)blockIdx.x; j++) off += bsum[j];
    blockoff = off;
  }
  int base = blockIdx.x * SCB + threadIdx.x * SCT;
  int v[SCT]; int s = 0;
#pragma unroll
  for (int j = 0; j < SCT; j++){ int i = base + j; v[j] = (i < M) ? gh[i] : 0; s += v[j]; }
  sh[threadIdx.x] = s;
  __syncthreads();
  for (int o = 1; o < 256; o <<= 1){
    int t = (threadIdx.x >= o) ? sh[threadIdx.x - o] : 0;
    __syncthreads();
    sh[threadIdx.x] += t;
    __syncthreads();
  }
  int excl = blockoff + sh[threadIdx.x] - s;
#pragma unroll
  for (int j = 0; j < SCT; j++){
    int i = base + j;
    if (i < M){ gh[i] = excl; excl += v[j]; }
  }
  if (blockIdx.x == 0 && threadIdx.x == 0) rp[N] = E;
}

template<bool POOL>
__global__ __launch_bounds__(256) void k_pscatter(const int* __restrict__ row, const int* __restrict__ col,
                                                  int E, int chunk, const int* __restrict__ gh,
                                                  unsigned* __restrict__ ebuf, int nbkt){
  __shared__ int cur[256];
  for (int i = threadIdx.x; i < nbkt; i += 256) cur[i] = gh[i * NBLK + blockIdx.x];
  __syncthreads();
  int e0 = blockIdx.x * chunk, e1 = min(E, e0 + chunk);
  for (int e = e0 + threadIdx.x; e < e1; e += 256){
    int r = row[e];
    int dst = atomicAdd(&cur[r >> 9], 1);
    unsigned pay = POOL ? (unsigned)e : (unsigned)col[e];
    ebuf[dst] = ((unsigned)(r & 511) << PAYB) | pay;
  }
}

template<bool POOL>
__global__ __launch_bounds__(512) void k_bfinal(const unsigned* __restrict__ ebuf,
                                                const int* __restrict__ gh, int nbkt, int N, int E,
                                                const int* __restrict__ pcol, const float* __restrict__ pval,
                                                int* __restrict__ rp, float* __restrict__ dinv,
                                                int* __restrict__ cs, float* __restrict__ wv){
  __shared__ int h[512];
  __shared__ int cur[512];
  int b = blockIdx.x;
  int e0 = gh[b * NBLK];
  int e1 = (b + 1 < nbkt) ? gh[(b + 1) * NBLK] : E;
  int r0 = b * RPB;
  int t = threadIdx.x;
  h[t] = 0;
  __syncthreads();
  for (int e = e0 + t; e < e1; e += 512)
    atomicAdd(&h[ebuf[e] >> PAYB], 1);
  __syncthreads();
  int cnt = h[t];
  __syncthreads();
  for (int o = 1; o < 512; o <<= 1){
    int tmp = (t >= o) ? h[t - o] : 0;
    __syncthreads();
    h[t] += tmp;
    __syncthreads();
  }
  int excl = h[t] - cnt;
  cur[t] = excl;
  if (r0 + t < N){
    rp[r0 + t] = e0 + excl;
    if (!POOL) dinv[r0 + t] = cnt > 0 ? rsqrtf((float)cnt) : 0.f;
  }
  __syncthreads();
  for (int e = e0 + t; e < e1; e += 512){
    unsigned u = ebuf[e];
    int p = atomicAdd(&cur[u >> PAYB], 1);
    int dst = e0 + p;
    if (POOL){
      int ei = (int)(u & ((1u << PAYB) - 1));
      cs[dst] = pcol[ei]; wv[dst] = pval[ei];
    } else {
      cs[dst] = (int)(u & ((1u << PAYB) - 1));
    }
  }
}

// ================= CSR gathers =================
__global__ __launch_bounds__(256) void k_gather3(const int* __restrict__ rp, const int* __restrict__ cs,
                          const float* __restrict__ src, const float* __restrict__ dinv,
                          const float* __restrict__ sub, float* __restrict__ dst,
                          int N, float scale){
  int n = blockIdx.x * blockDim.x + threadIdx.x;
  if (n >= N) return;
  int e0 = rp[n], e1 = rp[n + 1];
  float a0 = 0.f, a1 = 0.f, a2 = 0.f;
  for (int e = e0; e < e1; e++){
    int c = cs[e];
    float w = dinv[c];
    const float* sp = src + c * 3;
    a0 = fmaf(w, sp[0], a0);
    a1 = fmaf(w, sp[1], a1);
    a2 = fmaf(w, sp[2], a2);
  }
  float m = -scale * dinv[n];
  float r0 = m * a0, r1 = m * a1, r2 = m * a2;
  if (sub){ r0 -= sub[n * 3 + 0]; r1 -= sub[n * 3 + 1]; r2 -= sub[n * 3 + 2]; }
  dst[n * 3 + 0] = r0; dst[n * 3 + 1] = r1; dst[n * 3 + 2] = r2;
}

// F multiple of 4; lane-group of L=F/4 per node, float4 per lane.
template<int F>
__global__ __launch_bounds__(256) void k_gatherT(const int* __restrict__ rp, const int* __restrict__ cs,
                          const float* __restrict__ src, const float* __restrict__ dinv,
                          const float* __restrict__ sub, float* __restrict__ dst,
                          int N, float scale){
  constexpr int L = F / 4;
  int tid = blockIdx.x * 256 + threadIdx.x;
  int n = tid / L, q = tid % L;
  if (n >= N) return;
  const float4* src4 = (const float4*)src;
  int e0 = rp[n], e1 = rp[n + 1];
  float4 acc = make_float4(0.f, 0.f, 0.f, 0.f);
  for (int e = e0; e < e1; e++){
    int c = cs[e];
    float w = dinv[c];
    float4 v = src4[(long)c * L + q];
    acc.x = fmaf(w, v.x, acc.x); acc.y = fmaf(w, v.y, acc.y);
    acc.z = fmaf(w, v.z, acc.z); acc.w = fmaf(w, v.w, acc.w);
  }
  float m = -scale * dinv[n];
  float4 r = make_float4(m * acc.x, m * acc.y, m * acc.z, m * acc.w);
  if (sub){
    float4 sv = ((const float4*)sub)[(long)n * L + q];
    r.x -= sv.x; r.y -= sv.y; r.z -= sv.z; r.w -= sv.w;
  }
  ((float4*)dst)[(long)n * L + q] = r;
}

template<int F>
__global__ __launch_bounds__(256) void k_gatherP(const int* __restrict__ rp, const int* __restrict__ cs,
                          const float* __restrict__ wv, const float* __restrict__ h,
                          float* __restrict__ dst, int N){
  constexpr int L = F / 4;
  int tid = blockIdx.x * 256 + threadIdx.x;
  int n = tid / L, q = tid % L;
  if (n >= N) return;
  const float4* h4 = (const float4*)h;
  int e0 = rp[n], e1 = rp[n + 1];
  float4 acc = make_float4(0.f, 0.f, 0.f, 0.f);
  for (int e = e0; e < e1; e++){
    int c = cs[e];
    float w = wv[e];
    float4 v = h4[(long)c * L + q];
    acc.x = fmaf(w, v.x, acc.x); acc.y = fmaf(w, v.y, acc.y);
    acc.z = fmaf(w, v.z, acc.z); acc.w = fmaf(w, v.w, acc.w);
  }
  ((float4*)dst)[(long)n * L + q] = acc;
}

// ================= dense cheb contraction (4 outputs/thread) =================
template<int F, int FO, bool RELU>
__global__ __launch_bounds__(256) void k_cheb_out(const float* __restrict__ x, const float* __restrict__ T, int N,
                           const float* __restrict__ W, const float* __restrict__ b,
                           float* __restrict__ out){
  constexpr int OQ = FO / 4;
  long t = (long)blockIdx.x * 256 + threadIdx.x;
  int n = (int)(t / OQ), q = (int)(t % OQ);
  if (n >= N) return;
  const float4* W4 = (const float4*)W;
  float4 acc = ((const float4*)b)[q];
  for (int k = 0; k < KCH; k++){
    const float* row = (k == 0) ? (x + (long)n * F) : (T + ((long)(k - 1) * N + n) * F);
    const float4* Wk = W4 + (long)k * F * OQ + q;
    for (int f = 0; f < F; f++){
      float v = row[f];
      float4 w = Wk[(long)f * OQ];
      acc.x = fmaf(v, w.x, acc.x); acc.y = fmaf(v, w.y, acc.y);
      acc.z = fmaf(v, w.z, acc.z); acc.w = fmaf(v, w.w, acc.w);
    }
  }
  if (RELU){
    acc.x = fmaxf(acc.x, 0.f); acc.y = fmaxf(acc.y, 0.f);
    acc.z = fmaxf(acc.z, 0.f); acc.w = fmaxf(acc.w, 0.f);
  }
  ((float4*)out)[(long)n * OQ + q] = acc;
}

// ================= final hidden GEMM + global max + classifier =================
__device__ __forceinline__ unsigned fmap(float x){
  unsigned u = __float_as_uint(x);
  return (u & 0x80000000u) ? ~u : (u | 0x80000000u);
}
__device__ __forceinline__ float funmap(unsigned u){
  return (u & 0x80000000u) ? __uint_as_float(u ^ 0x80000000u) : __uint_as_float(~u);
}

__global__ void k_init_max(unsigned* __restrict__ m){
  m[blockIdx.x * blockDim.x + threadIdx.x] = fmap(-INFINITY);
}

#define NB 25
__global__ __launch_bounds__(256) void k_hidden_max(const float* __restrict__ h2, const float* __restrict__ Wh,
                             const float* __restrict__ bh, unsigned* __restrict__ maxed, int N){
  __shared__ float sh[NB * 128];
  int o  = blockIdx.x * 256 + threadIdx.x;
  int n0 = blockIdx.y * NB;
  for (int i = threadIdx.x; i < NB * 128; i += 256){
    int n = n0 + i / 128;
    sh[i] = (n < N) ? h2[(long)n * 128 + (i & 127)] : 0.f;
  }
  __syncthreads();
  float acc[NB];
#pragma unroll
  for (int n = 0; n < NB; n++) acc[n] = 0.f;
  for (int f = 0; f < 128; f++){
    float w = Wh[(long)f * 1024 + o];
#pragma unroll
    for (int n = 0; n < NB; n++) acc[n] = fmaf(sh[n * 128 + f], w, acc[n]);
  }
  float bo = bh[o];
  float m = -INFINITY;
#pragma unroll
  for (int n = 0; n < NB; n++)
    if (n0 + n < N) m = fmaxf(m, acc[n] + bo);
  atomicMax(&maxed[o], fmap(m));
}

__global__ void k_final(const unsigned* __restrict__ maxed, const float* __restrict__ Wl,
                        const float* __restrict__ bl, float* __restrict__ out){
  int c = threadIdx.x;
  if (c >= NCLS) return;
  float acc = bl[c];
  for (int o = 0; o < 1024; o++)
    acc = fmaf(funmap(maxed[o]), Wl[o * NCLS + c], acc);
  out[c] = acc;
}

// ================= drivers =================
static void run_scan(int* gh, int M, int* bsum, int* rp, int N, int E, hipStream_t s){
  int nb = cdiv(M, SCB);
  k_scanA<<<nb, 256, 0, s>>>(gh, M, bsum);
  k_scanC<<<nb, 256, 0, s>>>(gh, M, bsum, rp, N, E);
}

template<int F, int FO, bool RELU>
static void run_cheb(const int* row, const int* col, int E, int N,
                     const float* x, const float* W, const float* b, float* out,
                     unsigned* ebuf, int* cs, float* T,
                     int* rp, float* dinv, int* gh, int* bsum, hipStream_t s){
  int nbkt = cdiv(N, RPB);
  int chunk = cdiv(E, NBLK);
  k_phist<<<NBLK, 256, 0, s>>>(row, E, chunk, gh, nbkt);
  run_scan(gh, nbkt * NBLK, bsum, rp, N, E, s);
  k_pscatter<false><<<NBLK, 256, 0, s>>>(row, col, E, chunk, gh, ebuf, nbkt);
  k_bfinal<false><<<nbkt, 512, 0, s>>>(ebuf, gh, nbkt, N, E, nullptr, nullptr, rp, dinv, cs, nullptr);

  const float* src = x; const float* sub = nullptr; float scale = 1.f;
  for (int k = 1; k < KCH; k++){
    float* Tk = T + (size_t)(k - 1) * N * F;
    if constexpr (F == 3)
      k_gather3<<<cdiv(N, 256), 256, 0, s>>>(rp, cs, src, dinv, sub, Tk, N, scale);
    else
      k_gatherT<F><<<cdiv((long)N * (F / 4), 256), 256, 0, s>>>(rp, cs, src, dinv, sub, Tk, N, scale);
    sub = src; src = Tk; scale = 2.f;
  }
  k_cheb_out<F, FO, RELU><<<cdiv((long)N * (FO / 4), 256), 256, 0, s>>>(x, T, N, W, b, out);
}

template<int F>
static void run_pool(const int* row, const int* col, const float* val, int E, int Nout,
                     const float* h, float* out, unsigned* ebuf, int* cs, float* wv,
                     int* rp, int* gh, int* bsum, hipStream_t s){
  int nbkt = cdiv(Nout, RPB);
  int chunk = cdiv(E, NBLK);
  k_phist<<<NBLK, 256, 0, s>>>(row, E, chunk, gh, nbkt);
  run_scan(gh, nbkt * NBLK, bsum, rp, Nout, E, s);
  k_pscatter<true><<<NBLK, 256, 0, s>>>(row, col, E, chunk, gh, ebuf, nbkt);
  k_bfinal<true><<<nbkt, 512, 0, s>>>(ebuf, gh, nbkt, Nout, E, col, val, rp, nullptr, cs, wv);
  k_gatherP<F><<<cdiv((long)Nout * (F / 4), 256), 256, 0, s>>>(rp, cs, wv, h, out, Nout);
}

extern "C" void kernel_launch(void* const* d_in, const int* in_sizes, int n_in,
                              void* d_out, int out_size, void* d_ws, size_t ws_size,
                              hipStream_t stream){
  const float* pos = (const float*)d_in[0];
  const int*   ei0 = (const int*)d_in[1];
  const int*   ei1 = (const int*)d_in[2];
  const int*   ei2 = (const int*)d_in[3];
  const int*   p0r = (const int*)d_in[4];
  const int*   p0c = (const int*)d_in[5];
  const float* p0v = (const float*)d_in[6];
  const int*   p1r = (const int*)d_in[7];
  const int*   p1c = (const int*)d_in[8];
  const float* p1v = (const float*)d_in[9];
  const float* W0  = (const float*)d_in[10]; const float* b0 = (const float*)d_in[11];
  const float* W1  = (const float*)d_in[12]; const float* b1 = (const float*)d_in[13];
  const float* W2  = (const float*)d_in[14]; const float* b2 = (const float*)d_in[15];
  const float* Wh  = (const float*)d_in[16]; const float* bh = (const float*)d_in[17];
  const float* Wl  = (const float*)d_in[18]; const float* bl = (const float*)d_in[19];
  float* out = (float*)d_out;

  // workspace layout (float-sized units)
  float* SCR = (float*)d_ws;                 // 4.8M floats, per-stage overlays
  float* hA  = SCR + 4800000;                // 3.2M  (N0*32 / N2*128)
  float* hB  = hA + 3200000;                 // 1.6M  (N1*64)
  float* hC  = hB + 1600000;                 // 0.8M  (N1*32 / N2*64)
  int* rp     = (int*)(hC + 800000);         // 100001
  float* dinv = (float*)(rp + 100001);       // 100000
  int* gh     = (int*)(dinv + 100000);       // 47040 (196*240 max)
  int* bsum   = gh + 47040;                  // 16
  unsigned* maxed = (unsigned*)(bsum + 16);  // 1024

  // layer 0: cheb(pos) -> hA [N0,32], relu.  SCR: ebuf 1.6M | cs 1.6M | T 1.5M
  run_cheb<3, 32, true>(ei0, ei0 + E0G, E0G, N0G, pos, W0, b0, hA,
                        (unsigned*)SCR, (int*)(SCR + 1600000), SCR + 3200000,
                        rp, dinv, gh, bsum, stream);

  // pool 0: hA -> hC [N1,32].  SCR: ebuf 100K | cs 100K | wv 100K
  run_pool<32>(p0r, p0c, p0v, N0G, N1G, hA, hC,
               (unsigned*)SCR, (int*)(SCR + 100000), SCR + 200000,
               rp, gh, bsum, stream);

  // layer 1: cheb(hC) -> hB [N1,64], relu.  SCR: ebuf 400K | cs 400K | T 4M
  run_cheb<32, 64, true>(ei1, ei1 + E1G, E1G, N1G, hC, W1, b1, hB,
                         (unsigned*)SCR, (int*)(SCR + 400000), SCR + 800000,
                         rp, dinv, gh, bsum, stream);

  // pool 1: hB -> hC [N2,64].  SCR: ebuf 25K | cs 25K | wv 25K
  run_pool<64>(p1r, p1c, p1v, N1G, N2G, hB, hC,
               (unsigned*)SCR, (int*)(SCR + 25000), SCR + 50000,
               rp, gh, bsum, stream);

  // layer 2: cheb(hC) -> hA [N2,128], no relu.  SCR: ebuf 100K | cs 100K | T 2M
  run_cheb<64, 128, false>(ei2, ei2 + E2G, E2G, N2G, hC, W2, b2, hA,
                           (unsigned*)SCR, (int*)(SCR + 100000), SCR + 200000,
                           rp, dinv, gh, bsum, stream);

  // hidden GEMM + global max over nodes
  k_init_max<<<4, 256, 0, stream>>>(maxed);
  dim3 g(4, 250);
  k_hidden_max<<<g, 256, 0, stream>>>(hA, Wh, bh, maxed, N2G);

  // classifier
  k_final<<<1, 64, 0, stream>>>(maxed, Wl, bl, out);
}

// Round 6
// 633.711 us; speedup vs baseline: 1.9533x; 1.0256x over previous
//
#include <hip/hip_runtime.h>
#include <cstdint>
#include <cmath>

#define N0G 100000
#define N1G 25000
#define N2G 6250
#define E0G 1600000
#define E1G 400000
#define E2G 100000
#define KCH 6
#define NCLS 40
#define RPB 512            // rows per bucket (9 bits local row)
#define NBLK 240           // binning blocks
#define PAYB 17            // payload bits (col or edge idx < 131072)
#define SCT 16             // scan elems per thread
#define SCB (256 * SCT)    // scan elems per block

static inline int cdiv(long a, long b){ return (int)((a + b - 1) / b); }

// ================= deterministic bucket CSR build =================
// entry = (row & 511) << 17 | payload.  payload = col (graph) or edge idx (pool)

__global__ __launch_bounds__(256) void k_phist(const int* __restrict__ row, int E, int chunk,
                                               int* __restrict__ gh, int nbkt){
  __shared__ int h[256];
  for (int i = threadIdx.x; i < nbkt; i += 256) h[i] = 0;
  __syncthreads();
  int e0 = blockIdx.x * chunk, e1 = min(E, e0 + chunk);
  for (int e = e0 + threadIdx.x; e < e1; e += 256)
    atomicAdd(&h[row[e] >> 9], 1);
  __syncthreads();
  for (int i = threadIdx.x; i < nbkt; i += 256)
    gh[i * NBLK + blockIdx.x] = h[i];
}

// parallel flat exclusive scan of gh[M]: A) per-block sums, C) offset + local scan
__global__ __launch_bounds__(256) void k_scanA(const int* __restrict__ gh, int M, int* __restrict__ bsum){
  __shared__ int sh[256];
  int base = blockIdx.x * SCB + threadIdx.x * SCT;
  int s = 0;
#pragma unroll
  for (int j = 0; j < SCT; j++){ int i = base + j; if (i < M) s += gh[i]; }
  sh[threadIdx.x] = s; __syncthreads();
  for (int o = 128; o > 0; o >>= 1){
    if (threadIdx.x < o) sh[threadIdx.x] += sh[threadIdx.x + o];
    __syncthreads();
  }
  if (threadIdx.x == 0) bsum[blockIdx.x] = sh[0];
}

__global__ __launch_bounds__(256) void k_scanC(int* __restrict__ gh, int M, const int* __restrict__ bsum,
                                               int* __restrict__ rp, int N, int E){
  __shared__ int sh[256];
  __shared__ int blockoff;
  if (threadIdx.x == 0){
    int off = 0;
    for (int j = 0; j < (int)blockIdx.x; j++) off += bsum[j];
    blockoff = off;
  }
  int base = blockIdx.x * SCB + threadIdx.x * SCT;
  int v[SCT]; int s = 0;
#pragma unroll
  for (int j = 0; j < SCT; j++){ int i = base + j; v[j] = (i < M) ? gh[i] : 0; s += v[j]; }
  sh[threadIdx.x] = s;
  __syncthreads();
  for (int o = 1; o < 256; o <<= 1){
    int t = (threadIdx.x >= o) ? sh[threadIdx.x - o] : 0;
    __syncthreads();
    sh[threadIdx.x] += t;
    __syncthreads();
  }
  int excl = blockoff + sh[threadIdx.x] - s;
#pragma unroll
  for (int j = 0; j < SCT; j++){
    int i = base + j;
    if (i < M){ gh[i] = excl; excl += v[j]; }
  }
  if (blockIdx.x == 0 && threadIdx.x == 0) rp[N] = E;
}

template<bool POOL>
__global__ __launch_bounds__(256) void k_pscatter(const int* __restrict__ row, const int* __restrict__ col,
                                                  int E, int chunk, const int* __restrict__ gh,
                                                  unsigned* __restrict__ ebuf, int nbkt){
  __shared__ int cur[256];
  for (int i = threadIdx.x; i < nbkt; i += 256) cur[i] = gh[i * NBLK + blockIdx.x];
  __syncthreads();
  int e0 = blockIdx.x * chunk, e1 = min(E, e0 + chunk);
  for (int e = e0 + threadIdx.x; e < e1; e += 256){
    int r = row[e];
    int dst = atomicAdd(&cur[r >> 9], 1);
    unsigned pay = POOL ? (unsigned)e : (unsigned)col[e];
    ebuf[dst] = ((unsigned)(r & 511) << PAYB) | pay;
  }
}

template<bool POOL>
__global__ __launch_bounds__(512) void k_bfinal(const unsigned* __restrict__ ebuf,
                                                const int* __restrict__ gh, int nbkt, int N, int E,
                                                const int* __restrict__ pcol, const float* __restrict__ pval,
                                                int* __restrict__ rp, float* __restrict__ dinv,
                                                int* __restrict__ cs, float* __restrict__ wv){
  __shared__ int h[512];
  __shared__ int cur[512];
  int b = blockIdx.x;
  int e0 = gh[b * NBLK];
  int e1 = (b + 1 < nbkt) ? gh[(b + 1) * NBLK] : E;
  int r0 = b * RPB;
  int t = threadIdx.x;
  h[t] = 0;
  __syncthreads();
  for (int e = e0 + t; e < e1; e += 512)
    atomicAdd(&h[ebuf[e] >> PAYB], 1);
  __syncthreads();
  int cnt = h[t];
  __syncthreads();
  for (int o = 1; o < 512; o <<= 1){
    int tmp = (t >= o) ? h[t - o] : 0;
    __syncthreads();
    h[t] += tmp;
    __syncthreads();
  }
  int excl = h[t] - cnt;
  cur[t] = excl;
  if (r0 + t < N){
    rp[r0 + t] = e0 + excl;
    if (!POOL) dinv[r0 + t] = cnt > 0 ? rsqrtf((float)cnt) : 0.f;
  }
  __syncthreads();
  for (int e = e0 + t; e < e1; e += 512){
    unsigned u = ebuf[e];
    int p = atomicAdd(&cur[u >> PAYB], 1);
    int dst = e0 + p;
    if (POOL){
      int ei = (int)(u & ((1u << PAYB) - 1));
      cs[dst] = pcol[ei]; wv[dst] = pval[ei];
    } else {
      cs[dst] = (int)(u & ((1u << PAYB) - 1));
    }
  }
}

// ================= CSR gathers =================
__global__ __launch_bounds__(256) void k_gather3(const int* __restrict__ rp, const int* __restrict__ cs,
                          const float* __restrict__ src, const float* __restrict__ dinv,
                          const float* __restrict__ sub, float* __restrict__ dst,
                          int N, float scale){
  int n = blockIdx.x * blockDim.x + threadIdx.x;
  if (n >= N) return;
  int e0 = rp[n], e1 = rp[n + 1];
  float a0 = 0.f, a1 = 0.f, a2 = 0.f;
  for (int e = e0; e < e1; e++){
    int c = cs[e];
    float w = dinv[c];
    const float* sp = src + c * 3;
    a0 = fmaf(w, sp[0], a0);
    a1 = fmaf(w, sp[1], a1);
    a2 = fmaf(w, sp[2], a2);
  }
  float m = -scale * dinv[n];
  float r0 = m * a0, r1 = m * a1, r2 = m * a2;
  if (sub){ r0 -= sub[n * 3 + 0]; r1 -= sub[n * 3 + 1]; r2 -= sub[n * 3 + 2]; }
  dst[n * 3 + 0] = r0; dst[n * 3 + 1] = r1; dst[n * 3 + 2] = r2;
}

// F multiple of 4; lane-group of L=F/4 per node, float4 per lane.
template<int F>
__global__ __launch_bounds__(256) void k_gatherT(const int* __restrict__ rp, const int* __restrict__ cs,
                          const float* __restrict__ src, const float* __restrict__ dinv,
                          const float* __restrict__ sub, float* __restrict__ dst,
                          int N, float scale){
  constexpr int L = F / 4;
  int tid = blockIdx.x * 256 + threadIdx.x;
  int n = tid / L, q = tid % L;
  if (n >= N) return;
  const float4* src4 = (const float4*)src;
  int e0 = rp[n], e1 = rp[n + 1];
  float4 acc = make_float4(0.f, 0.f, 0.f, 0.f);
  for (int e = e0; e < e1; e++){
    int c = cs[e];
    float w = dinv[c];
    float4 v = src4[(long)c * L + q];
    acc.x = fmaf(w, v.x, acc.x); acc.y = fmaf(w, v.y, acc.y);
    acc.z = fmaf(w, v.z, acc.z); acc.w = fmaf(w, v.w, acc.w);
  }
  float m = -scale * dinv[n];
  float4 r = make_float4(m * acc.x, m * acc.y, m * acc.z, m * acc.w);
  if (sub){
    float4 sv = ((const float4*)sub)[(long)n * L + q];
    r.x -= sv.x; r.y -= sv.y; r.z -= sv.z; r.w -= sv.w;
  }
  ((float4*)dst)[(long)n * L + q] = r;
}

template<int F>
__global__ __launch_bounds__(256) void k_gatherP(const int* __restrict__ rp, const int* __restrict__ cs,
                          const float* __restrict__ wv, const float* __restrict__ h,
                          float* __restrict__ dst, int N){
  constexpr int L = F / 4;
  int tid = blockIdx.x * 256 + threadIdx.x;
  int n = tid / L, q = tid % L;
  if (n >= N) return;
  const float4* h4 = (const float4*)h;
  int e0 = rp[n], e1 = rp[n + 1];
  float4 acc = make_float4(0.f, 0.f, 0.f, 0.f);
  for (int e = e0; e < e1; e++){
    int c = cs[e];
    float w = wv[e];
    float4 v = h4[(long)c * L + q];
    acc.x = fmaf(w, v.x, acc.x); acc.y = fmaf(w, v.y, acc.y);
    acc.z = fmaf(w, v.z, acc.z); acc.w = fmaf(w, v.w, acc.w);
  }
  ((float4*)dst)[(long)n * L + q] = acc;
}

// ================= dense cheb contraction (4 outputs/thread) =================
template<int F, int FO, bool RELU>
__global__ __launch_bounds__(256) void k_cheb_out(const float* __restrict__ x, const float* __restrict__ T, int N,
                           const float* __restrict__ W, const float* __restrict__ b,
                           float* __restrict__ out){
  constexpr int OQ = FO / 4;
  long t = (long)blockIdx.x * 256 + threadIdx.x;
  int n = (int)(t / OQ), q = (int)(t % OQ);
  if (n >= N) return;
  const float4* W4 = (const float4*)W;
  float4 acc = ((const float4*)b)[q];
  for (int k = 0; k < KCH; k++){
    const float* row = (k == 0) ? (x + (long)n * F) : (T + ((long)(k - 1) * N + n) * F);
    const float4* Wk = W4 + (long)k * F * OQ + q;
    for (int f = 0; f < F; f++){
      float v = row[f];
      float4 w = Wk[(long)f * OQ];
      acc.x = fmaf(v, w.x, acc.x); acc.y = fmaf(v, w.y, acc.y);
      acc.z = fmaf(v, w.z, acc.z); acc.w = fmaf(v, w.w, acc.w);
    }
  }
  if (RELU){
    acc.x = fmaxf(acc.x, 0.f); acc.y = fmaxf(acc.y, 0.f);
    acc.z = fmaxf(acc.z, 0.f); acc.w = fmaxf(acc.w, 0.f);
  }
  ((float4*)out)[(long)n * OQ + q] = acc;
}

// ================= final hidden GEMM + global max + classifier =================
__device__ __forceinline__ unsigned fmap(float x){
  unsigned u = __float_as_uint(x);
  return (u & 0x80000000u) ? ~u : (u | 0x80000000u);
}
__device__ __forceinline__ float funmap(unsigned u){
  return (u & 0x80000000u) ? __uint_as_float(u ^ 0x80000000u) : __uint_as_float(~u);
}

// 250 blocks x 256 threads; each block: NT nodes x all 1024 outputs.
// LDS transposed tile shT[f][n], rows padded to 28 floats (16B-aligned) so
// consecutive-n reads merge to broadcast ds_read_b128.
#define NT 25
#define NTP 28
__global__ __launch_bounds__(256) void k_hidden_max(const float* __restrict__ h2, const float* __restrict__ Wh,
                             const float* __restrict__ bh, unsigned* __restrict__ maxed, int N){
  __shared__ float shT[128][NTP];
  int n0 = blockIdx.x * NT;
  for (int i = threadIdx.x; i < NT * 32; i += 256){
    int n = i >> 5, f4 = i & 31;
    float4 v = make_float4(0.f, 0.f, 0.f, 0.f);
    if (n0 + n < N) v = ((const float4*)h2)[(long)(n0 + n) * 32 + f4];
    shT[f4 * 4 + 0][n] = v.x; shT[f4 * 4 + 1][n] = v.y;
    shT[f4 * 4 + 2][n] = v.z; shT[f4 * 4 + 3][n] = v.w;
  }
  __syncthreads();
  int o4 = threadIdx.x;                 // float4 output index, o = 4*o4
  float4 acc[NT];
#pragma unroll
  for (int n = 0; n < NT; n++) acc[n] = make_float4(0.f, 0.f, 0.f, 0.f);
  const float4* Wh4 = (const float4*)Wh;
  for (int f = 0; f < 128; f++){
    float4 w = Wh4[(long)f * 256 + o4];
#pragma unroll
    for (int n = 0; n < NT; n++){
      float v = shT[f][n];
      acc[n].x = fmaf(v, w.x, acc[n].x);
      acc[n].y = fmaf(v, w.y, acc[n].y);
      acc[n].z = fmaf(v, w.z, acc[n].z);
      acc[n].w = fmaf(v, w.w, acc[n].w);
    }
  }
  int lim = min(NT, N - n0);
  float4 m = make_float4(-INFINITY, -INFINITY, -INFINITY, -INFINITY);
#pragma unroll
  for (int n = 0; n < NT; n++){
    if (n < lim){
      m.x = fmaxf(m.x, acc[n].x); m.y = fmaxf(m.y, acc[n].y);
      m.z = fmaxf(m.z, acc[n].z); m.w = fmaxf(m.w, acc[n].w);
    }
  }
  float4 b4 = ((const float4*)bh)[o4];
  m.x += b4.x; m.y += b4.y; m.z += b4.z; m.w += b4.w;
  atomicMax(&maxed[4 * o4 + 0], fmap(m.x));
  atomicMax(&maxed[4 * o4 + 1], fmap(m.y));
  atomicMax(&maxed[4 * o4 + 2], fmap(m.z));
  atomicMax(&maxed[4 * o4 + 3], fmap(m.w));
}

// 40 blocks (one per class) x 64 lanes; wave shuffle reduce.
__global__ __launch_bounds__(64) void k_final(const unsigned* __restrict__ maxed, const float* __restrict__ Wl,
                        const float* __restrict__ bl, float* __restrict__ out){
  int c = blockIdx.x;
  int l = threadIdx.x;
  float acc = 0.f;
  for (int o = l; o < 1024; o += 64)
    acc = fmaf(funmap(maxed[o]), Wl[o * NCLS + c], acc);
  for (int off = 32; off > 0; off >>= 1)
    acc += __shfl_down(acc, off);
  if (l == 0) out[c] = acc + bl[c];
}

// ================= drivers =================
static void run_scan(int* gh, int M, int* bsum, int* rp, int N, int E, hipStream_t s){
  int nb = cdiv(M, SCB);
  k_scanA<<<nb, 256, 0, s>>>(gh, M, bsum);
  k_scanC<<<nb, 256, 0, s>>>(gh, M, bsum, rp, N, E);
}

template<int F, int FO, bool RELU>
static void run_cheb(const int* row, const int* col, int E, int N,
                     const float* x, const float* W, const float* b, float* out,
                     unsigned* ebuf, int* cs, float* T,
                     int* rp, float* dinv, int* gh, int* bsum, hipStream_t s){
  int nbkt = cdiv(N, RPB);
  int chunk = cdiv(E, NBLK);
  k_phist<<<NBLK, 256, 0, s>>>(row, E, chunk, gh, nbkt);
  run_scan(gh, nbkt * NBLK, bsum, rp, N, E, s);
  k_pscatter<false><<<NBLK, 256, 0, s>>>(row, col, E, chunk, gh, ebuf, nbkt);
  k_bfinal<false><<<nbkt, 512, 0, s>>>(ebuf, gh, nbkt, N, E, nullptr, nullptr, rp, dinv, cs, nullptr);

  const float* src = x; const float* sub = nullptr; float scale = 1.f;
  for (int k = 1; k < KCH; k++){
    float* Tk = T + (size_t)(k - 1) * N * F;
    if constexpr (F == 3)
      k_gather3<<<cdiv(N, 256), 256, 0, s>>>(rp, cs, src, dinv, sub, Tk, N, scale);
    else
      k_gatherT<F><<<cdiv((long)N * (F / 4), 256), 256, 0, s>>>(rp, cs, src, dinv, sub, Tk, N, scale);
    sub = src; src = Tk; scale = 2.f;
  }
  k_cheb_out<F, FO, RELU><<<cdiv((long)N * (FO / 4), 256), 256, 0, s>>>(x, T, N, W, b, out);
}

template<int F>
static void run_pool(const int* row, const int* col, const float* val, int E, int Nout,
                     const float* h, float* out, unsigned* ebuf, int* cs, float* wv,
                     int* rp, int* gh, int* bsum, hipStream_t s){
  int nbkt = cdiv(Nout, RPB);
  int chunk = cdiv(E, NBLK);
  k_phist<<<NBLK, 256, 0, s>>>(row, E, chunk, gh, nbkt);
  run_scan(gh, nbkt * NBLK, bsum, rp, Nout, E, s);
  k_pscatter<true><<<NBLK, 256, 0, s>>>(row, col, E, chunk, gh, ebuf, nbkt);
  k_bfinal<true><<<nbkt, 512, 0, s>>>(ebuf, gh, nbkt, Nout, E, col, val, rp, nullptr, cs, wv);
  k_gatherP<F><<<cdiv((long)Nout * (F / 4), 256), 256, 0, s>>>(rp, cs, wv, h, out, Nout);
}

extern "C" void kernel_launch(void* const* d_in, const int* in_sizes, int n_in,
                              void* d_out, int out_size, void* d_ws, size_t ws_size,
                              hipStream_t stream){
  const float* pos = (const float*)d_in[0];
  const int*   ei0 = (const int*)d_in[1];
  const int*   ei1 = (const int*)d_in[2];
  const int*   ei2 = (const int*)d_in[3];
  const int*   p0r = (const int*)d_in[4];
  const int*   p0c = (const int*)d_in[5];
  const float* p0v = (const float*)d_in[6];
  const int*   p1r = (const int*)d_in[7];
  const int*   p1c = (const int*)d_in[8];
  const float* p1v = (const float*)d_in[9];
  const float* W0  = (const float*)d_in[10]; const float* b0 = (const float*)d_in[11];
  const float* W1  = (const float*)d_in[12]; const float* b1 = (const float*)d_in[13];
  const float* W2  = (const float*)d_in[14]; const float* b2 = (const float*)d_in[15];
  const float* Wh  = (const float*)d_in[16]; const float* bh = (const float*)d_in[17];
  const float* Wl  = (const float*)d_in[18]; const float* bl = (const float*)d_in[19];
  float* out = (float*)d_out;

  // workspace layout (float-sized units)
  float* SCR = (float*)d_ws;                 // 4.8M floats, per-stage overlays
  float* hA  = SCR + 4800000;                // 3.2M  (N0*32 / N2*128)
  float* hB  = hA + 3200000;                 // 1.6M  (N1*64)
  float* hC  = hB + 1600000;                 // 0.8M  (N1*32 / N2*64)
  int* rp     = (int*)(hC + 800000);         // 100001
  float* dinv = (float*)(rp + 100001);       // 100000
  int* gh     = (int*)(dinv + 100000);       // 47040 (196*240 max)
  int* bsum   = gh + 47040;                  // 16
  unsigned* maxed = (unsigned*)(bsum + 16);  // 1024

  // layer 0: cheb(pos) -> hA [N0,32], relu.  SCR: ebuf 1.6M | cs 1.6M | T 1.5M
  run_cheb<3, 32, true>(ei0, ei0 + E0G, E0G, N0G, pos, W0, b0, hA,
                        (unsigned*)SCR, (int*)(SCR + 1600000), SCR + 3200000,
                        rp, dinv, gh, bsum, stream);

  // pool 0: hA -> hC [N1,32].  SCR: ebuf 100K | cs 100K | wv 100K
  run_pool<32>(p0r, p0c, p0v, N0G, N1G, hA, hC,
               (unsigned*)SCR, (int*)(SCR + 100000), SCR + 200000,
               rp, gh, bsum, stream);

  // layer 1: cheb(hC) -> hB [N1,64], relu.  SCR: ebuf 400K | cs 400K | T 4M
  run_cheb<32, 64, true>(ei1, ei1 + E1G, E1G, N1G, hC, W1, b1, hB,
                         (unsigned*)SCR, (int*)(SCR + 400000), SCR + 800000,
                         rp, dinv, gh, bsum, stream);

  // pool 1: hB -> hC [N2,64].  SCR: ebuf 25K | cs 25K | wv 25K
  run_pool<64>(p1r, p1c, p1v, N1G, N2G, hB, hC,
               (unsigned*)SCR, (int*)(SCR + 25000), SCR + 50000,
               rp, gh, bsum, stream);

  // layer 2: cheb(hC) -> hA [N2,128], no relu.  SCR: ebuf 100K | cs 100K | T 2M
  run_cheb<64, 128, false>(ei2, ei2 + E2G, E2G, N2G, hC, W2, b2, hA,
                           (unsigned*)SCR, (int*)(SCR + 100000), SCR + 200000,
                           rp, dinv, gh, bsum, stream);

  // hidden GEMM + global max over nodes
  hipMemsetAsync(maxed, 0, 1024 * sizeof(unsigned), stream);
  k_hidden_max<<<cdiv(N2G, NT), 256, 0, stream>>>(hA, Wh, bh, maxed, N2G);

  // classifier
  k_final<<<NCLS, 64, 0, stream>>>(maxed, Wl, bl, out);
}

// Round 7
// 602.575 us; speedup vs baseline: 2.0542x; 1.0517x over previous
//
#include <hip/hip_runtime.h>
#include <cstdint>
#include <cmath>

#define N0G 100000
#define N1G 25000
#define N2G 6250
#define E0G 1600000
#define E1G 400000
#define E2G 100000
#define KCH 6
#define NCLS 40
#define RPB 512            // rows per bucket (9 bits local row)
#define NBLK 240           // binning blocks
#define PAYB 17            // payload bits (col or edge idx < 131072)
#define SCT 16             // scan elems per thread
#define SCB (256 * SCT)    // scan elems per block

static inline int cdiv(long a, long b){ return (int)((a + b - 1) / b); }

// ================= deterministic bucket CSR build =================
// entry = (row & 511) << 17 | payload.  payload = col (graph) or edge idx (pool)

__global__ __launch_bounds__(256) void k_phist(const int* __restrict__ row, int E, int chunk,
                                               int* __restrict__ gh, int nbkt){
  __shared__ int h[256];
  for (int i = threadIdx.x; i < nbkt; i += 256) h[i] = 0;
  __syncthreads();
  int e0 = blockIdx.x * chunk, e1 = min(E, e0 + chunk);
  for (int e = e0 + threadIdx.x; e < e1; e += 256)
    atomicAdd(&h[row[e] >> 9], 1);
  __syncthreads();
  for (int i = threadIdx.x; i < nbkt; i += 256)
    gh[i * NBLK + blockIdx.x] = h[i];
}

// parallel flat exclusive scan of gh[M]: A) per-block sums, C) offset + local scan
__global__ __launch_bounds__(256) void k_scanA(const int* __restrict__ gh, int M, int* __restrict__ bsum){
  __shared__ int sh[256];
  int base = blockIdx.x * SCB + threadIdx.x * SCT;
  int s = 0;
#pragma unroll
  for (int j = 0; j < SCT; j++){ int i = base + j; if (i < M) s += gh[i]; }
  sh[threadIdx.x] = s; __syncthreads();
  for (int o = 128; o > 0; o >>= 1){
    if (threadIdx.x < o) sh[threadIdx.x] += sh[threadIdx.x + o];
    __syncthreads();
  }
  if (threadIdx.x == 0) bsum[blockIdx.x] = sh[0];
}

__global__ __launch_bounds__(256) void k_scanC(int* __restrict__ gh, int M, const int* __restrict__ bsum,
                                               int* __restrict__ rp, int N, int E){
  __shared__ int sh[256];
  __shared__ int blockoff;
  if (threadIdx.x == 0){
    int off = 0;
    for (int j = 0; j < (int)blockIdx.x; j++) off += bsum[j];
    blockoff = off;
  }
  int base = blockIdx.x * SCB + threadIdx.x * SCT;
  int v[SCT]; int s = 0;
#pragma unroll
  for (int j = 0; j < SCT; j++){ int i = base + j; v[j] = (i < M) ? gh[i] : 0; s += v[j]; }
  sh[threadIdx.x] = s;
  __syncthreads();
  for (int o = 1; o < 256; o <<= 1){
    int t = (threadIdx.x >= o) ? sh[threadIdx.x - o] : 0;
    __syncthreads();
    sh[threadIdx.x] += t;
    __syncthreads();
  }
  int excl = blockoff + sh[threadIdx.x] - s;
#pragma unroll
  for (int j = 0; j < SCT; j++){
    int i = base + j;
    if (i < M){ gh[i] = excl; excl += v[j]; }
  }
  if (blockIdx.x == 0 && threadIdx.x == 0) rp[N] = E;
}

template<bool POOL>
__global__ __launch_bounds__(256) void k_pscatter(const int* __restrict__ row, const int* __restrict__ col,
                                                  int E, int chunk, const int* __restrict__ gh,
                                                  unsigned* __restrict__ ebuf, int nbkt){
  __shared__ int cur[256];
  for (int i = threadIdx.x; i < nbkt; i += 256) cur[i] = gh[i * NBLK + blockIdx.x];
  __syncthreads();
  int e0 = blockIdx.x * chunk, e1 = min(E, e0 + chunk);
  for (int e = e0 + threadIdx.x; e < e1; e += 256){
    int r = row[e];
    int dst = atomicAdd(&cur[r >> 9], 1);
    unsigned pay = POOL ? (unsigned)e : (unsigned)col[e];
    ebuf[dst] = ((unsigned)(r & 511) << PAYB) | pay;
  }
}

template<bool POOL>
__global__ __launch_bounds__(512) void k_bfinal(const unsigned* __restrict__ ebuf,
                                                const int* __restrict__ gh, int nbkt, int N, int E,
                                                const int* __restrict__ pcol, const float* __restrict__ pval,
                                                int* __restrict__ rp, float* __restrict__ dinv,
                                                int* __restrict__ cs, float* __restrict__ wv){
  __shared__ int h[512];
  __shared__ int cur[512];
  int b = blockIdx.x;
  int e0 = gh[b * NBLK];
  int e1 = (b + 1 < nbkt) ? gh[(b + 1) * NBLK] : E;
  int r0 = b * RPB;
  int t = threadIdx.x;
  h[t] = 0;
  __syncthreads();
  for (int e = e0 + t; e < e1; e += 512)
    atomicAdd(&h[ebuf[e] >> PAYB], 1);
  __syncthreads();
  int cnt = h[t];
  __syncthreads();
  for (int o = 1; o < 512; o <<= 1){
    int tmp = (t >= o) ? h[t - o] : 0;
    __syncthreads();
    h[t] += tmp;
    __syncthreads();
  }
  int excl = h[t] - cnt;
  cur[t] = excl;
  if (r0 + t < N){
    rp[r0 + t] = e0 + excl;
    if (!POOL) dinv[r0 + t] = cnt > 0 ? rsqrtf((float)cnt) : 0.f;
  }
  __syncthreads();
  for (int e = e0 + t; e < e1; e += 512){
    unsigned u = ebuf[e];
    int p = atomicAdd(&cur[u >> PAYB], 1);
    int dst = e0 + p;
    if (POOL){
      int ei = (int)(u & ((1u << PAYB) - 1));
      cs[dst] = pcol[ei]; wv[dst] = pval[ei];
    } else {
      cs[dst] = (int)(u & ((1u << PAYB) - 1));
    }
  }
}

// ================= CSR gathers =================
__global__ __launch_bounds__(256) void k_gather3(const int* __restrict__ rp, const int* __restrict__ cs,
                          const float* __restrict__ src, const float* __restrict__ dinv,
                          const float* __restrict__ sub, float* __restrict__ dst,
                          int N, float scale){
  int n = blockIdx.x * blockDim.x + threadIdx.x;
  if (n >= N) return;
  int e0 = rp[n], e1 = rp[n + 1];
  float a0 = 0.f, a1 = 0.f, a2 = 0.f;
  for (int e = e0; e < e1; e++){
    int c = cs[e];
    float w = dinv[c];
    const float* sp = src + c * 3;
    a0 = fmaf(w, sp[0], a0);
    a1 = fmaf(w, sp[1], a1);
    a2 = fmaf(w, sp[2], a2);
  }
  float m = -scale * dinv[n];
  float r0 = m * a0, r1 = m * a1, r2 = m * a2;
  if (sub){ r0 -= sub[n * 3 + 0]; r1 -= sub[n * 3 + 1]; r2 -= sub[n * 3 + 2]; }
  dst[n * 3 + 0] = r0; dst[n * 3 + 1] = r1; dst[n * 3 + 2] = r2;
}

// F multiple of 4; lane-group of L=F/4 per node, float4 per lane.
template<int F>
__global__ __launch_bounds__(256) void k_gatherT(const int* __restrict__ rp, const int* __restrict__ cs,
                          const float* __restrict__ src, const float* __restrict__ dinv,
                          const float* __restrict__ sub, float* __restrict__ dst,
                          int N, float scale){
  constexpr int L = F / 4;
  int tid = blockIdx.x * 256 + threadIdx.x;
  int n = tid / L, q = tid % L;
  if (n >= N) return;
  const float4* src4 = (const float4*)src;
  int e0 = rp[n], e1 = rp[n + 1];
  float4 acc = make_float4(0.f, 0.f, 0.f, 0.f);
  for (int e = e0; e < e1; e++){
    int c = cs[e];
    float w = dinv[c];
    float4 v = src4[(long)c * L + q];
    acc.x = fmaf(w, v.x, acc.x); acc.y = fmaf(w, v.y, acc.y);
    acc.z = fmaf(w, v.z, acc.z); acc.w = fmaf(w, v.w, acc.w);
  }
  float m = -scale * dinv[n];
  float4 r = make_float4(m * acc.x, m * acc.y, m * acc.z, m * acc.w);
  if (sub){
    float4 sv = ((const float4*)sub)[(long)n * L + q];
    r.x -= sv.x; r.y -= sv.y; r.z -= sv.z; r.w -= sv.w;
  }
  ((float4*)dst)[(long)n * L + q] = r;
}

template<int F>
__global__ __launch_bounds__(256) void k_gatherP(const int* __restrict__ rp, const int* __restrict__ cs,
                          const float* __restrict__ wv, const float* __restrict__ h,
                          float* __restrict__ dst, int N){
  constexpr int L = F / 4;
  int tid = blockIdx.x * 256 + threadIdx.x;
  int n = tid / L, q = tid % L;
  if (n >= N) return;
  const float4* h4 = (const float4*)h;
  int e0 = rp[n], e1 = rp[n + 1];
  float4 acc = make_float4(0.f, 0.f, 0.f, 0.f);
  for (int e = e0; e < e1; e++){
    int c = cs[e];
    float w = wv[e];
    float4 v = h4[(long)c * L + q];
    acc.x = fmaf(w, v.x, acc.x); acc.y = fmaf(w, v.y, acc.y);
    acc.z = fmaf(w, v.z, acc.z); acc.w = fmaf(w, v.w, acc.w);
  }
  ((float4*)dst)[(long)n * L + q] = acc;
}

// ================= dense cheb contraction (4 outputs/thread) =================
template<int F, int FO, bool RELU>
__global__ __launch_bounds__(256) void k_cheb_out(const float* __restrict__ x, const float* __restrict__ T, int N,
                           const float* __restrict__ W, const float* __restrict__ b,
                           float* __restrict__ out){
  constexpr int OQ = FO / 4;
  long t = (long)blockIdx.x * 256 + threadIdx.x;
  int n = (int)(t / OQ), q = (int)(t % OQ);
  if (n >= N) return;
  const float4* W4 = (const float4*)W;
  float4 acc = ((const float4*)b)[q];
  for (int k = 0; k < KCH; k++){
    const float* row = (k == 0) ? (x + (long)n * F) : (T + ((long)(k - 1) * N + n) * F);
    const float4* Wk = W4 + (long)k * F * OQ + q;
    for (int f = 0; f < F; f++){
      float v = row[f];
      float4 w = Wk[(long)f * OQ];
      acc.x = fmaf(v, w.x, acc.x); acc.y = fmaf(v, w.y, acc.y);
      acc.z = fmaf(v, w.z, acc.z); acc.w = fmaf(v, w.w, acc.w);
    }
  }
  if (RELU){
    acc.x = fmaxf(acc.x, 0.f); acc.y = fmaxf(acc.y, 0.f);
    acc.z = fmaxf(acc.z, 0.f); acc.w = fmaxf(acc.w, 0.f);
  }
  ((float4*)out)[(long)n * OQ + q] = acc;
}

// ================= final hidden GEMM + global max + classifier =================
__device__ __forceinline__ unsigned fmap(float x){
  unsigned u = __float_as_uint(x);
  return (u & 0x80000000u) ? ~u : (u | 0x80000000u);
}
__device__ __forceinline__ float funmap(unsigned u){
  return (u & 0x80000000u) ? __uint_as_float(u ^ 0x80000000u) : __uint_as_float(~u);
}

// block = 32 nodes x 256 outputs. thread = 1 float4 output x 8 nodes (acc[8] = 32 VGPR).
// h-tile in LDS natural [n][f4] float4 layout: staging = coalesced copy,
// reads = wave-broadcast ds_read_b128 (no transpose, no conflicts).
#define NT 32
__global__ __launch_bounds__(256) void k_hidden_max(const float* __restrict__ h2, const float* __restrict__ Wh,
                             const float* __restrict__ bh, unsigned* __restrict__ maxed, int N){
  __shared__ float4 sh4[NT * 32];        // 16 KB
  int n0 = blockIdx.y * NT;
  for (int i = threadIdx.x; i < NT * 32; i += 256){
    int n = i >> 5;
    float4 v = make_float4(0.f, 0.f, 0.f, 0.f);
    if (n0 + n < N) v = ((const float4*)h2)[(long)(n0 + n) * 32 + (i & 31)];
    sh4[i] = v;
  }
  __syncthreads();
  int o4l  = threadIdx.x & 63;           // o4 within tile
  int nsub = threadIdx.x >> 6;           // 0..3, 8 nodes each
  int o4   = blockIdx.x * 64 + o4l;      // global float4 output index
  const float4* Wh4 = (const float4*)Wh;
  float4 acc[8];
#pragma unroll
  for (int j = 0; j < 8; j++) acc[j] = make_float4(0.f, 0.f, 0.f, 0.f);
  for (int f4 = 0; f4 < 32; f4++){
    float4 w0 = Wh4[(long)(4 * f4 + 0) * 256 + o4];
    float4 w1 = Wh4[(long)(4 * f4 + 1) * 256 + o4];
    float4 w2 = Wh4[(long)(4 * f4 + 2) * 256 + o4];
    float4 w3 = Wh4[(long)(4 * f4 + 3) * 256 + o4];
#pragma unroll
    for (int j = 0; j < 8; j++){
      float4 hv = sh4[(nsub * 8 + j) * 32 + f4];
      acc[j].x = fmaf(hv.x, w0.x, acc[j].x); acc[j].y = fmaf(hv.x, w0.y, acc[j].y);
      acc[j].z = fmaf(hv.x, w0.z, acc[j].z); acc[j].w = fmaf(hv.x, w0.w, acc[j].w);
      acc[j].x = fmaf(hv.y, w1.x, acc[j].x); acc[j].y = fmaf(hv.y, w1.y, acc[j].y);
      acc[j].z = fmaf(hv.y, w1.z, acc[j].z); acc[j].w = fmaf(hv.y, w1.w, acc[j].w);
      acc[j].x = fmaf(hv.z, w2.x, acc[j].x); acc[j].y = fmaf(hv.z, w2.y, acc[j].y);
      acc[j].z = fmaf(hv.z, w2.z, acc[j].z); acc[j].w = fmaf(hv.z, w2.w, acc[j].w);
      acc[j].x = fmaf(hv.w, w3.x, acc[j].x); acc[j].y = fmaf(hv.w, w3.y, acc[j].y);
      acc[j].z = fmaf(hv.w, w3.z, acc[j].z); acc[j].w = fmaf(hv.w, w3.w, acc[j].w);
    }
  }
  float4 m = make_float4(-INFINITY, -INFINITY, -INFINITY, -INFINITY);
#pragma unroll
  for (int j = 0; j < 8; j++){
    if (n0 + nsub * 8 + j < N){
      m.x = fmaxf(m.x, acc[j].x); m.y = fmaxf(m.y, acc[j].y);
      m.z = fmaxf(m.z, acc[j].z); m.w = fmaxf(m.w, acc[j].w);
    }
  }
  // cross-nsub reduce via LDS (reuse sh4), then one atomicMax per output
  __syncthreads();
  sh4[nsub * 64 + o4l] = m;
  __syncthreads();
  if (nsub == 0){
#pragma unroll
    for (int s = 1; s < 4; s++){
      float4 o = sh4[s * 64 + o4l];
      m.x = fmaxf(m.x, o.x); m.y = fmaxf(m.y, o.y);
      m.z = fmaxf(m.z, o.z); m.w = fmaxf(m.w, o.w);
    }
    float4 b4 = ((const float4*)bh)[o4];
    atomicMax(&maxed[4 * o4 + 0], fmap(m.x + b4.x));
    atomicMax(&maxed[4 * o4 + 1], fmap(m.y + b4.y));
    atomicMax(&maxed[4 * o4 + 2], fmap(m.z + b4.z));
    atomicMax(&maxed[4 * o4 + 3], fmap(m.w + b4.w));
  }
}

// 40 blocks (one per class) x 64 lanes; wave shuffle reduce.
__global__ __launch_bounds__(64) void k_final(const unsigned* __restrict__ maxed, const float* __restrict__ Wl,
                        const float* __restrict__ bl, float* __restrict__ out){
  int c = blockIdx.x;
  int l = threadIdx.x;
  float acc = 0.f;
  for (int o = l; o < 1024; o += 64)
    acc = fmaf(funmap(maxed[o]), Wl[o * NCLS + c], acc);
  for (int off = 32; off > 0; off >>= 1)
    acc += __shfl_down(acc, off);
  if (l == 0) out[c] = acc + bl[c];
}

// ================= drivers =================
static void run_scan(int* gh, int M, int* bsum, int* rp, int N, int E, hipStream_t s){
  int nb = cdiv(M, SCB);
  k_scanA<<<nb, 256, 0, s>>>(gh, M, bsum);
  k_scanC<<<nb, 256, 0, s>>>(gh, M, bsum, rp, N, E);
}

template<int F, int FO, bool RELU>
static void run_cheb(const int* row, const int* col, int E, int N,
                     const float* x, const float* W, const float* b, float* out,
                     unsigned* ebuf, int* cs, float* T,
                     int* rp, float* dinv, int* gh, int* bsum, hipStream_t s){
  int nbkt = cdiv(N, RPB);
  int chunk = cdiv(E, NBLK);
  k_phist<<<NBLK, 256, 0, s>>>(row, E, chunk, gh, nbkt);
  run_scan(gh, nbkt * NBLK, bsum, rp, N, E, s);
  k_pscatter<false><<<NBLK, 256, 0, s>>>(row, col, E, chunk, gh, ebuf, nbkt);
  k_bfinal<false><<<nbkt, 512, 0, s>>>(ebuf, gh, nbkt, N, E, nullptr, nullptr, rp, dinv, cs, nullptr);

  const float* src = x; const float* sub = nullptr; float scale = 1.f;
  for (int k = 1; k < KCH; k++){
    float* Tk = T + (size_t)(k - 1) * N * F;
    if constexpr (F == 3)
      k_gather3<<<cdiv(N, 256), 256, 0, s>>>(rp, cs, src, dinv, sub, Tk, N, scale);
    else
      k_gatherT<F><<<cdiv((long)N * (F / 4), 256), 256, 0, s>>>(rp, cs, src, dinv, sub, Tk, N, scale);
    sub = src; src = Tk; scale = 2.f;
  }
  k_cheb_out<F, FO, RELU><<<cdiv((long)N * (FO / 4), 256), 256, 0, s>>>(x, T, N, W, b, out);
}

template<int F>
static void run_pool(const int* row, const int* col, const float* val, int E, int Nout,
                     const float* h, float* out, unsigned* ebuf, int* cs, float* wv,
                     int* rp, int* gh, int* bsum, hipStream_t s){
  int nbkt = cdiv(Nout, RPB);
  int chunk = cdiv(E, NBLK);
  k_phist<<<NBLK, 256, 0, s>>>(row, E, chunk, gh, nbkt);
  run_scan(gh, nbkt * NBLK, bsum, rp, Nout, E, s);
  k_pscatter<true><<<NBLK, 256, 0, s>>>(row, col, E, chunk, gh, ebuf, nbkt);
  k_bfinal<true><<<nbkt, 512, 0, s>>>(ebuf, gh, nbkt, Nout, E, col, val, rp, nullptr, cs, wv);
  k_gatherP<F><<<cdiv((long)Nout * (F / 4), 256), 256, 0, s>>>(rp, cs, wv, h, out, Nout);
}

extern "C" void kernel_launch(void* const* d_in, const int* in_sizes, int n_in,
                              void* d_out, int out_size, void* d_ws, size_t ws_size,
                              hipStream_t stream){
  const float* pos = (const float*)d_in[0];
  const int*   ei0 = (const int*)d_in[1];
  const int*   ei1 = (const int*)d_in[2];
  const int*   ei2 = (const int*)d_in[3];
  const int*   p0r = (const int*)d_in[4];
  const int*   p0c = (const int*)d_in[5];
  const float* p0v = (const float*)d_in[6];
  const int*   p1r = (const int*)d_in[7];
  const int*   p1c = (const int*)d_in[8];
  const float* p1v = (const float*)d_in[9];
  const float* W0  = (const float*)d_in[10]; const float* b0 = (const float*)d_in[11];
  const float* W1  = (const float*)d_in[12]; const float* b1 = (const float*)d_in[13];
  const float* W2  = (const float*)d_in[14]; const float* b2 = (const float*)d_in[15];
  const float* Wh  = (const float*)d_in[16]; const float* bh = (const float*)d_in[17];
  const float* Wl  = (const float*)d_in[18]; const float* bl = (const float*)d_in[19];
  float* out = (float*)d_out;

  // workspace layout (float-sized units)
  float* SCR = (float*)d_ws;                 // 4.8M floats, per-stage overlays
  float* hA  = SCR + 4800000;                // 3.2M  (N0*32 / N2*128)
  float* hB  = hA + 3200000;                 // 1.6M  (N1*64)
  float* hC  = hB + 1600000;                 // 0.8M  (N1*32 / N2*64)
  int* rp     = (int*)(hC + 800000);         // 100001
  float* dinv = (float*)(rp + 100001);       // 100000
  int* gh     = (int*)(dinv + 100000);       // 47040 (196*240 max)
  int* bsum   = gh + 47040;                  // 16
  unsigned* maxed = (unsigned*)(bsum + 16);  // 1024

  // layer 0: cheb(pos) -> hA [N0,32], relu.  SCR: ebuf 1.6M | cs 1.6M | T 1.5M
  run_cheb<3, 32, true>(ei0, ei0 + E0G, E0G, N0G, pos, W0, b0, hA,
                        (unsigned*)SCR, (int*)(SCR + 1600000), SCR + 3200000,
                        rp, dinv, gh, bsum, stream);

  // pool 0: hA -> hC [N1,32].  SCR: ebuf 100K | cs 100K | wv 100K
  run_pool<32>(p0r, p0c, p0v, N0G, N1G, hA, hC,
               (unsigned*)SCR, (int*)(SCR + 100000), SCR + 200000,
               rp, gh, bsum, stream);

  // layer 1: cheb(hC) -> hB [N1,64], relu.  SCR: ebuf 400K | cs 400K | T 4M
  run_cheb<32, 64, true>(ei1, ei1 + E1G, E1G, N1G, hC, W1, b1, hB,
                         (unsigned*)SCR, (int*)(SCR + 400000), SCR + 800000,
                         rp, dinv, gh, bsum, stream);

  // pool 1: hB -> hC [N2,64].  SCR: ebuf 25K | cs 25K | wv 25K
  run_pool<64>(p1r, p1c, p1v, N1G, N2G, hB, hC,
               (unsigned*)SCR, (int*)(SCR + 25000), SCR + 50000,
               rp, gh, bsum, stream);

  // layer 2: cheb(hC) -> hA [N2,128], no relu.  SCR: ebuf 100K | cs 100K | T 2M
  run_cheb<64, 128, false>(ei2, ei2 + E2G, E2G, N2G, hC, W2, b2, hA,
                           (unsigned*)SCR, (int*)(SCR + 100000), SCR + 200000,
                           rp, dinv, gh, bsum, stream);

  // hidden GEMM + global max over nodes
  hipMemsetAsync(maxed, 0, 1024 * sizeof(unsigned), stream);
  dim3 g(4, cdiv(N2G, NT));
  k_hidden_max<<<g, 256, 0, stream>>>(hA, Wh, bh, maxed, N2G);

  // classifier
  k_final<<<NCLS, 64, 0, stream>>>(maxed, Wl, bl, out);
}

// Round 8
// 553.405 us; speedup vs baseline: 2.2368x; 1.0888x over previous
//
#include <hip/hip_runtime.h>
#include <cstdint>
#include <cmath>

#define N0G 100000
#define N1G 25000
#define N2G 6250
#define E0G 1600000
#define E1G 400000
#define E2G 100000
#define KCH 6
#define NCLS 40
#define RPB 512            // rows per bucket (9 bits local row)
#define NBLK 240           // binning blocks
#define PAYB 17            // payload bits (col or edge idx < 131072)
#define SCT 16             // scan elems per thread
#define SCB (256 * SCT)    // scan elems per block

static inline int cdiv(long a, long b){ return (int)((a + b - 1) / b); }

// ================= deterministic bucket CSR build =================
// entry = (row & 511) << 17 | payload.  payload = col (graph) or edge idx (pool)

__global__ __launch_bounds__(256) void k_phist(const int* __restrict__ row, int E, int chunk,
                                               int* __restrict__ gh, int nbkt){
  __shared__ int h[256];
  for (int i = threadIdx.x; i < nbkt; i += 256) h[i] = 0;
  __syncthreads();
  int e0 = blockIdx.x * chunk, e1 = min(E, e0 + chunk);
  for (int e = e0 + threadIdx.x; e < e1; e += 256)
    atomicAdd(&h[row[e] >> 9], 1);
  __syncthreads();
  for (int i = threadIdx.x; i < nbkt; i += 256)
    gh[i * NBLK + blockIdx.x] = h[i];
}

// parallel flat exclusive scan of gh[M]: A) per-block sums, C) offset + local scan
__global__ __launch_bounds__(256) void k_scanA(const int* __restrict__ gh, int M, int* __restrict__ bsum){
  __shared__ int sh[256];
  int base = blockIdx.x * SCB + threadIdx.x * SCT;
  int s = 0;
#pragma unroll
  for (int j = 0; j < SCT; j++){ int i = base + j; if (i < M) s += gh[i]; }
  sh[threadIdx.x] = s; __syncthreads();
  for (int o = 128; o > 0; o >>= 1){
    if (threadIdx.x < o) sh[threadIdx.x] += sh[threadIdx.x + o];
    __syncthreads();
  }
  if (threadIdx.x == 0) bsum[blockIdx.x] = sh[0];
}

__global__ __launch_bounds__(256) void k_scanC(int* __restrict__ gh, int M, const int* __restrict__ bsum,
                                               int* __restrict__ rp, int N, int E){
  __shared__ int sh[256];
  __shared__ int blockoff;
  if (threadIdx.x == 0){
    int off = 0;
    for (int j = 0; j < (int)blockIdx.x; j++) off += bsum[j];
    blockoff = off;
  }
  int base = blockIdx.x * SCB + threadIdx.x * SCT;
  int v[SCT]; int s = 0;
#pragma unroll
  for (int j = 0; j < SCT; j++){ int i = base + j; v[j] = (i < M) ? gh[i] : 0; s += v[j]; }
  sh[threadIdx.x] = s;
  __syncthreads();
  for (int o = 1; o < 256; o <<= 1){
    int t = (threadIdx.x >= o) ? sh[threadIdx.x - o] : 0;
    __syncthreads();
    sh[threadIdx.x] += t;
    __syncthreads();
  }
  int excl = blockoff + sh[threadIdx.x] - s;
#pragma unroll
  for (int j = 0; j < SCT; j++){
    int i = base + j;
    if (i < M){ gh[i] = excl; excl += v[j]; }
  }
  if (blockIdx.x == 0 && threadIdx.x == 0) rp[N] = E;
}

template<bool POOL>
__global__ __launch_bounds__(256) void k_pscatter(const int* __restrict__ row, const int* __restrict__ col,
                                                  int E, int chunk, const int* __restrict__ gh,
                                                  unsigned* __restrict__ ebuf, int nbkt){
  __shared__ int cur[256];
  for (int i = threadIdx.x; i < nbkt; i += 256) cur[i] = gh[i * NBLK + blockIdx.x];
  __syncthreads();
  int e0 = blockIdx.x * chunk, e1 = min(E, e0 + chunk);
  for (int e = e0 + threadIdx.x; e < e1; e += 256){
    int r = row[e];
    int dst = atomicAdd(&cur[r >> 9], 1);
    unsigned pay = POOL ? (unsigned)e : (unsigned)col[e];
    ebuf[dst] = ((unsigned)(r & 511) << PAYB) | pay;
  }
}

template<bool POOL>
__global__ __launch_bounds__(512) void k_bfinal(const unsigned* __restrict__ ebuf,
                                                const int* __restrict__ gh, int nbkt, int N, int E,
                                                const int* __restrict__ pcol, const float* __restrict__ pval,
                                                int* __restrict__ rp, float* __restrict__ dinv,
                                                int* __restrict__ cs, float* __restrict__ wv){
  __shared__ int h[512];
  __shared__ int cur[512];
  int b = blockIdx.x;
  int e0 = gh[b * NBLK];
  int e1 = (b + 1 < nbkt) ? gh[(b + 1) * NBLK] : E;
  int r0 = b * RPB;
  int t = threadIdx.x;
  h[t] = 0;
  __syncthreads();
  for (int e = e0 + t; e < e1; e += 512)
    atomicAdd(&h[ebuf[e] >> PAYB], 1);
  __syncthreads();
  int cnt = h[t];
  __syncthreads();
  for (int o = 1; o < 512; o <<= 1){
    int tmp = (t >= o) ? h[t - o] : 0;
    __syncthreads();
    h[t] += tmp;
    __syncthreads();
  }
  int excl = h[t] - cnt;
  cur[t] = excl;
  if (r0 + t < N){
    rp[r0 + t] = e0 + excl;
    if (!POOL) dinv[r0 + t] = cnt > 0 ? rsqrtf((float)cnt) : 0.f;
  }
  __syncthreads();
  for (int e = e0 + t; e < e1; e += 512){
    unsigned u = ebuf[e];
    int p = atomicAdd(&cur[u >> PAYB], 1);
    int dst = e0 + p;
    if (POOL){
      int ei = (int)(u & ((1u << PAYB) - 1));
      cs[dst] = pcol[ei]; wv[dst] = pval[ei];
    } else {
      cs[dst] = (int)(u & ((1u << PAYB) - 1));
    }
  }
}

// ================= CSR gathers =================
__global__ __launch_bounds__(256) void k_gather3(const int* __restrict__ rp, const int* __restrict__ cs,
                          const float* __restrict__ src, const float* __restrict__ dinv,
                          const float* __restrict__ sub, float* __restrict__ dst,
                          int N, float scale){
  int n = blockIdx.x * blockDim.x + threadIdx.x;
  if (n >= N) return;
  int e0 = rp[n], e1 = rp[n + 1];
  float a0 = 0.f, a1 = 0.f, a2 = 0.f;
  for (int e = e0; e < e1; e++){
    int c = cs[e];
    float w = dinv[c];
    const float* sp = src + c * 3;
    a0 = fmaf(w, sp[0], a0);
    a1 = fmaf(w, sp[1], a1);
    a2 = fmaf(w, sp[2], a2);
  }
  float m = -scale * dinv[n];
  float r0 = m * a0, r1 = m * a1, r2 = m * a2;
  if (sub){ r0 -= sub[n * 3 + 0]; r1 -= sub[n * 3 + 1]; r2 -= sub[n * 3 + 2]; }
  dst[n * 3 + 0] = r0; dst[n * 3 + 1] = r1; dst[n * 3 + 2] = r2;
}

// F multiple of 4; lane-group of L=F/4 per node, float4 per lane.
template<int F>
__global__ __launch_bounds__(256) void k_gatherT(const int* __restrict__ rp, const int* __restrict__ cs,
                          const float* __restrict__ src, const float* __restrict__ dinv,
                          const float* __restrict__ sub, float* __restrict__ dst,
                          int N, float scale){
  constexpr int L = F / 4;
  int tid = blockIdx.x * 256 + threadIdx.x;
  int n = tid / L, q = tid % L;
  if (n >= N) return;
  const float4* src4 = (const float4*)src;
  int e0 = rp[n], e1 = rp[n + 1];
  float4 acc = make_float4(0.f, 0.f, 0.f, 0.f);
  for (int e = e0; e < e1; e++){
    int c = cs[e];
    float w = dinv[c];
    float4 v = src4[(long)c * L + q];
    acc.x = fmaf(w, v.x, acc.x); acc.y = fmaf(w, v.y, acc.y);
    acc.z = fmaf(w, v.z, acc.z); acc.w = fmaf(w, v.w, acc.w);
  }
  float m = -scale * dinv[n];
  float4 r = make_float4(m * acc.x, m * acc.y, m * acc.z, m * acc.w);
  if (sub){
    float4 sv = ((const float4*)sub)[(long)n * L + q];
    r.x -= sv.x; r.y -= sv.y; r.z -= sv.z; r.w -= sv.w;
  }
  ((float4*)dst)[(long)n * L + q] = r;
}

template<int F>
__global__ __launch_bounds__(256) void k_gatherP(const int* __restrict__ rp, const int* __restrict__ cs,
                          const float* __restrict__ wv, const float* __restrict__ h,
                          float* __restrict__ dst, int N){
  constexpr int L = F / 4;
  int tid = blockIdx.x * 256 + threadIdx.x;
  int n = tid / L, q = tid % L;
  if (n >= N) return;
  const float4* h4 = (const float4*)h;
  int e0 = rp[n], e1 = rp[n + 1];
  float4 acc = make_float4(0.f, 0.f, 0.f, 0.f);
  for (int e = e0; e < e1; e++){
    int c = cs[e];
    float w = wv[e];
    float4 v = h4[(long)c * L + q];
    acc.x = fmaf(w, v.x, acc.x); acc.y = fmaf(w, v.y, acc.y);
    acc.z = fmaf(w, v.z, acc.z); acc.w = fmaf(w, v.w, acc.w);
  }
  ((float4*)dst)[(long)n * L + q] = acc;
}

// ================= dense cheb contraction, LDS-tiled =================
// C[N, FO] = X6[N, 6F] @ W[6F, FO] + b,  X6 row = concat(x_row, T1..T5 rows).
// Block: NT = (256/(FO/4)) * R nodes. X6 tile staged in LDS (pitch +4 dwords).
// W read direct from global (L1/L2 resident), coalesced across o4 lanes.
template<int F, int FO, int R, bool RELU>
__global__ __launch_bounds__(256) void k_cheb_tile(const float* __restrict__ x, const float* __restrict__ T, int N,
                           const float* __restrict__ W, const float* __restrict__ b,
                           float* __restrict__ out){
  constexpr int OQ4  = FO / 4;
  constexpr int NSUB = 256 / OQ4;
  constexpr int NT   = NSUB * R;
  constexpr int F6   = KCH * F;
  constexpr int PITCH = F6 + 4;      // dwords; +4 keeps float4 alignment, skews banks
  __shared__ float X[NT * PITCH];
  int n0 = blockIdx.x * NT;

  if constexpr (F == 3){
    // scalar staging: slab k is a contiguous run of NT*F floats at rows n0..
    for (int i = threadIdx.x; i < NT * F6; i += 256){
      int k = i / (NT * F);
      int idx = i - k * (NT * F);
      int node = idx / F, j = idx - node * F;
      const float* src = (k == 0) ? x : (T + (size_t)(k - 1) * N * F);
      float v = (n0 + node < N) ? src[(long)n0 * F + idx] : 0.f;
      X[node * PITCH + k * F + j] = v;
    }
  } else {
    constexpr int L = F / 4;
    for (int i = threadIdx.x; i < NT * KCH * L; i += 256){
      int k = i / (NT * L);
      int idx = i - k * (NT * L);
      int node = idx / L, q = idx - node * L;
      const float4* src4 = (const float4*)((k == 0) ? x : (T + (size_t)(k - 1) * N * F));
      float4 v = make_float4(0.f, 0.f, 0.f, 0.f);
      if (n0 + node < N) v = src4[(long)n0 * L + idx];
      *(float4*)&X[node * PITCH + k * F + 4 * q] = v;
    }
  }
  __syncthreads();

  int o4   = threadIdx.x & (OQ4 - 1);
  int nsub = threadIdx.x >> (OQ4 == 8 ? 3 : (OQ4 == 16 ? 4 : 5));
  const float4* W4 = (const float4*)W;       // [F6][OQ4]
  float4 bb = ((const float4*)b)[o4];
  float4 acc[R];
#pragma unroll
  for (int r = 0; r < R; r++) acc[r] = bb;

#pragma unroll 4
  for (int f = 0; f < F6; f++){
    float4 w = W4[(long)f * OQ4 + o4];
#pragma unroll
    for (int r = 0; r < R; r++){
      float v = X[(nsub * R + r) * PITCH + f];
      acc[r].x = fmaf(v, w.x, acc[r].x); acc[r].y = fmaf(v, w.y, acc[r].y);
      acc[r].z = fmaf(v, w.z, acc[r].z); acc[r].w = fmaf(v, w.w, acc[r].w);
    }
  }
#pragma unroll
  for (int r = 0; r < R; r++){
    int n = n0 + nsub * R + r;
    if (n < N){
      float4 o = acc[r];
      if (RELU){
        o.x = fmaxf(o.x, 0.f); o.y = fmaxf(o.y, 0.f);
        o.z = fmaxf(o.z, 0.f); o.w = fmaxf(o.w, 0.f);
      }
      ((float4*)out)[(long)n * OQ4 + o4] = o;
    }
  }
}

// ================= final hidden GEMM + global max + classifier =================
__device__ __forceinline__ unsigned fmap(float x){
  unsigned u = __float_as_uint(x);
  return (u & 0x80000000u) ? ~u : (u | 0x80000000u);
}
__device__ __forceinline__ float funmap(unsigned u){
  return (u & 0x80000000u) ? __uint_as_float(u ^ 0x80000000u) : __uint_as_float(~u);
}

// block = 32 nodes x 256 outputs. thread = 1 float4 output x 8 nodes (acc[8] = 32 VGPR).
#define NT 32
__global__ __launch_bounds__(256) void k_hidden_max(const float* __restrict__ h2, const float* __restrict__ Wh,
                             const float* __restrict__ bh, unsigned* __restrict__ maxed, int N){
  __shared__ float4 sh4[NT * 32];        // 16 KB
  int n0 = blockIdx.y * NT;
  for (int i = threadIdx.x; i < NT * 32; i += 256){
    int n = i >> 5;
    float4 v = make_float4(0.f, 0.f, 0.f, 0.f);
    if (n0 + n < N) v = ((const float4*)h2)[(long)(n0 + n) * 32 + (i & 31)];
    sh4[i] = v;
  }
  __syncthreads();
  int o4l  = threadIdx.x & 63;           // o4 within tile
  int nsub = threadIdx.x >> 6;           // 0..3, 8 nodes each
  int o4   = blockIdx.x * 64 + o4l;      // global float4 output index
  const float4* Wh4 = (const float4*)Wh;
  float4 acc[8];
#pragma unroll
  for (int j = 0; j < 8; j++) acc[j] = make_float4(0.f, 0.f, 0.f, 0.f);
  for (int f4 = 0; f4 < 32; f4++){
    float4 w0 = Wh4[(long)(4 * f4 + 0) * 256 + o4];
    float4 w1 = Wh4[(long)(4 * f4 + 1) * 256 + o4];
    float4 w2 = Wh4[(long)(4 * f4 + 2) * 256 + o4];
    float4 w3 = Wh4[(long)(4 * f4 + 3) * 256 + o4];
#pragma unroll
    for (int j = 0; j < 8; j++){
      float4 hv = sh4[(nsub * 8 + j) * 32 + f4];
      acc[j].x = fmaf(hv.x, w0.x, acc[j].x); acc[j].y = fmaf(hv.x, w0.y, acc[j].y);
      acc[j].z = fmaf(hv.x, w0.z, acc[j].z); acc[j].w = fmaf(hv.x, w0.w, acc[j].w);
      acc[j].x = fmaf(hv.y, w1.x, acc[j].x); acc[j].y = fmaf(hv.y, w1.y, acc[j].y);
      acc[j].z = fmaf(hv.y, w1.z, acc[j].z); acc[j].w = fmaf(hv.y, w1.w, acc[j].w);
      acc[j].x = fmaf(hv.z, w2.x, acc[j].x); acc[j].y = fmaf(hv.z, w2.y, acc[j].y);
      acc[j].z = fmaf(hv.z, w2.z, acc[j].z); acc[j].w = fmaf(hv.z, w2.w, acc[j].w);
      acc[j].x = fmaf(hv.w, w3.x, acc[j].x); acc[j].y = fmaf(hv.w, w3.y, acc[j].y);
      acc[j].z = fmaf(hv.w, w3.z, acc[j].z); acc[j].w = fmaf(hv.w, w3.w, acc[j].w);
    }
  }
  float4 m = make_float4(-INFINITY, -INFINITY, -INFINITY, -INFINITY);
#pragma unroll
  for (int j = 0; j < 8; j++){
    if (n0 + nsub * 8 + j < N){
      m.x = fmaxf(m.x, acc[j].x); m.y = fmaxf(m.y, acc[j].y);
      m.z = fmaxf(m.z, acc[j].z); m.w = fmaxf(m.w, acc[j].w);
    }
  }
  __syncthreads();
  sh4[nsub * 64 + o4l] = m;
  __syncthreads();
  if (nsub == 0){
#pragma unroll
    for (int s = 1; s < 4; s++){
      float4 o = sh4[s * 64 + o4l];
      m.x = fmaxf(m.x, o.x); m.y = fmaxf(m.y, o.y);
      m.z = fmaxf(m.z, o.z); m.w = fmaxf(m.w, o.w);
    }
    float4 b4 = ((const float4*)bh)[o4];
    atomicMax(&maxed[4 * o4 + 0], fmap(m.x + b4.x));
    atomicMax(&maxed[4 * o4 + 1], fmap(m.y + b4.y));
    atomicMax(&maxed[4 * o4 + 2], fmap(m.z + b4.z));
    atomicMax(&maxed[4 * o4 + 3], fmap(m.w + b4.w));
  }
}

// 40 blocks (one per class) x 64 lanes; wave shuffle reduce.
__global__ __launch_bounds__(64) void k_final(const unsigned* __restrict__ maxed, const float* __restrict__ Wl,
                        const float* __restrict__ bl, float* __restrict__ out){
  int c = blockIdx.x;
  int l = threadIdx.x;
  float acc = 0.f;
  for (int o = l; o < 1024; o += 64)
    acc = fmaf(funmap(maxed[o]), Wl[o * NCLS + c], acc);
  for (int off = 32; off > 0; off >>= 1)
    acc += __shfl_down(acc, off);
  if (l == 0) out[c] = acc + bl[c];
}

// ================= drivers =================
static void run_scan(int* gh, int M, int* bsum, int* rp, int N, int E, hipStream_t s){
  int nb = cdiv(M, SCB);
  k_scanA<<<nb, 256, 0, s>>>(gh, M, bsum);
  k_scanC<<<nb, 256, 0, s>>>(gh, M, bsum, rp, N, E);
}

template<int F, int FO, int R, bool RELU>
static void run_cheb(const int* row, const int* col, int E, int N,
                     const float* x, const float* W, const float* b, float* out,
                     unsigned* ebuf, int* cs, float* T,
                     int* rp, float* dinv, int* gh, int* bsum, hipStream_t s){
  int nbkt = cdiv(N, RPB);
  int chunk = cdiv(E, NBLK);
  k_phist<<<NBLK, 256, 0, s>>>(row, E, chunk, gh, nbkt);
  run_scan(gh, nbkt * NBLK, bsum, rp, N, E, s);
  k_pscatter<false><<<NBLK, 256, 0, s>>>(row, col, E, chunk, gh, ebuf, nbkt);
  k_bfinal<false><<<nbkt, 512, 0, s>>>(ebuf, gh, nbkt, N, E, nullptr, nullptr, rp, dinv, cs, nullptr);

  const float* src = x; const float* sub = nullptr; float scale = 1.f;
  for (int k = 1; k < KCH; k++){
    float* Tk = T + (size_t)(k - 1) * N * F;
    if constexpr (F == 3)
      k_gather3<<<cdiv(N, 256), 256, 0, s>>>(rp, cs, src, dinv, sub, Tk, N, scale);
    else
      k_gatherT<F><<<cdiv((long)N * (F / 4), 256), 256, 0, s>>>(rp, cs, src, dinv, sub, Tk, N, scale);
    sub = src; src = Tk; scale = 2.f;
  }
  constexpr int NTC = (256 / (FO / 4)) * R;
  k_cheb_tile<F, FO, R, RELU><<<cdiv(N, NTC), 256, 0, s>>>(x, T, N, W, b, out);
}

template<int F>
static void run_pool(const int* row, const int* col, const float* val, int E, int Nout,
                     const float* h, float* out, unsigned* ebuf, int* cs, float* wv,
                     int* rp, int* gh, int* bsum, hipStream_t s){
  int nbkt = cdiv(Nout, RPB);
  int chunk = cdiv(E, NBLK);
  k_phist<<<NBLK, 256, 0, s>>>(row, E, chunk, gh, nbkt);
  run_scan(gh, nbkt * NBLK, bsum, rp, Nout, E, s);
  k_pscatter<true><<<NBLK, 256, 0, s>>>(row, col, E, chunk, gh, ebuf, nbkt);
  k_bfinal<true><<<nbkt, 512, 0, s>>>(ebuf, gh, nbkt, Nout, E, col, val, rp, nullptr, cs, wv);
  k_gatherP<F><<<cdiv((long)Nout * (F / 4), 256), 256, 0, s>>>(rp, cs, wv, h, out, Nout);
}

extern "C" void kernel_launch(void* const* d_in, const int* in_sizes, int n_in,
                              void* d_out, int out_size, void* d_ws, size_t ws_size,
                              hipStream_t stream){
  const float* pos = (const float*)d_in[0];
  const int*   ei0 = (const int*)d_in[1];
  const int*   ei1 = (const int*)d_in[2];
  const int*   ei2 = (const int*)d_in[3];
  const int*   p0r = (const int*)d_in[4];
  const int*   p0c = (const int*)d_in[5];
  const float* p0v = (const float*)d_in[6];
  const int*   p1r = (const int*)d_in[7];
  const int*   p1c = (const int*)d_in[8];
  const float* p1v = (const float*)d_in[9];
  const float* W0  = (const float*)d_in[10]; const float* b0 = (const float*)d_in[11];
  const float* W1  = (const float*)d_in[12]; const float* b1 = (const float*)d_in[13];
  const float* W2  = (const float*)d_in[14]; const float* b2 = (const float*)d_in[15];
  const float* Wh  = (const float*)d_in[16]; const float* bh = (const float*)d_in[17];
  const float* Wl  = (const float*)d_in[18]; const float* bl = (const float*)d_in[19];
  float* out = (float*)d_out;

  // workspace layout (float-sized units)
  float* SCR = (float*)d_ws;                 // 4.8M floats, per-stage overlays
  float* hA  = SCR + 4800000;                // 3.2M  (N0*32 / N2*128)
  float* hB  = hA + 3200000;                 // 1.6M  (N1*64)
  float* hC  = hB + 1600000;                 // 0.8M  (N1*32 / N2*64)
  int* rp     = (int*)(hC + 800000);         // 100001
  float* dinv = (float*)(rp + 100001);       // 100000
  int* gh     = (int*)(dinv + 100000);       // 47040 (196*240 max)
  int* bsum   = gh + 47040;                  // 16
  unsigned* maxed = (unsigned*)(bsum + 16);  // 1024

  // layer 0: cheb(pos) -> hA [N0,32], relu.  SCR: ebuf 1.6M | cs 1.6M | T 1.5M
  run_cheb<3, 32, 1, true>(ei0, ei0 + E0G, E0G, N0G, pos, W0, b0, hA,
                        (unsigned*)SCR, (int*)(SCR + 1600000), SCR + 3200000,
                        rp, dinv, gh, bsum, stream);

  // pool 0: hA -> hC [N1,32].  SCR: ebuf 100K | cs 100K | wv 100K
  run_pool<32>(p0r, p0c, p0v, N0G, N1G, hA, hC,
               (unsigned*)SCR, (int*)(SCR + 100000), SCR + 200000,
               rp, gh, bsum, stream);

  // layer 1: cheb(hC) -> hB [N1,64], relu.  SCR: ebuf 400K | cs 400K | T 4M
  run_cheb<32, 64, 2, true>(ei1, ei1 + E1G, E1G, N1G, hC, W1, b1, hB,
                         (unsigned*)SCR, (int*)(SCR + 400000), SCR + 800000,
                         rp, dinv, gh, bsum, stream);

  // pool 1: hB -> hC [N2,64].  SCR: ebuf 25K | cs 25K | wv 25K
  run_pool<64>(p1r, p1c, p1v, N1G, N2G, hB, hC,
               (unsigned*)SCR, (int*)(SCR + 25000), SCR + 50000,
               rp, gh, bsum, stream);

  // layer 2: cheb(hC) -> hA [N2,128], no relu.  SCR: ebuf 100K | cs 100K | T 2M
  run_cheb<64, 128, 2, false>(ei2, ei2 + E2G, E2G, N2G, hC, W2, b2, hA,
                           (unsigned*)SCR, (int*)(SCR + 100000), SCR + 200000,
                           rp, dinv, gh, bsum, stream);

  // hidden GEMM + global max over nodes
  hipMemsetAsync(maxed, 0, 1024 * sizeof(unsigned), stream);
  dim3 g(4, cdiv(N2G, NT));
  k_hidden_max<<<g, 256, 0, stream>>>(hA, Wh, bh, maxed, N2G);

  // classifier
  k_final<<<NCLS, 64, 0, stream>>>(maxed, Wl, bl, out);
}